// Round 1
// baseline (7157.497 us; speedup 1.0000x reference)
//
#include <hip/hip_runtime.h>

#define NWIN 128       // B * nW windows
#define NTOK 392       // tokens per window (8*7*7)
#define SPAT 25088     // D*H*W
#define NELEM 4816896  // 2*96*25088

// ---------- helpers ----------
__device__ __forceinline__ unsigned int f2bf(float f) {
  unsigned int u = __float_as_uint(f);
  return (u + 0x7fffu + ((u >> 16) & 1u)) >> 16;   // RNE to bf16
}
__device__ __forceinline__ unsigned int pack2(float a, float b) {
  return f2bf(a) | (f2bf(b) << 16);
}
__device__ __forceinline__ float bflo(unsigned int u) { return __uint_as_float(u << 16); }
__device__ __forceinline__ float bfhi(unsigned int u) { return __uint_as_float(u & 0xffff0000u); }

__device__ __forceinline__ float wmax64(float v) {
  #pragma unroll
  for (int o = 32; o > 0; o >>= 1) v = fmaxf(v, __shfl_xor(v, o, 64));
  return v;
}
__device__ __forceinline__ float wsum64(float v) {
  #pragma unroll
  for (int o = 32; o > 0; o >>= 1) v += __shfl_xor(v, o, 64);
  return v;
}

// ---------- kernel 1: LN1 over C + roll(-4,-3,-3) + window partition ----------
__global__ __launch_bounds__(128)
void k_ln1_win(const float* __restrict__ x, const float* __restrict__ lw,
               const float* __restrict__ lb, float* __restrict__ xw) {
  __shared__ float s1[128], s2[128];
  int t = blockIdx.x;                 // destination token
  int win = t / NTOK, n = t % NTOK;
  int b = win >> 6, wrem = win & 63;
  int hwin = wrem >> 3, wwin = wrem & 7;
  int ld = n / 49, r = n % 49, lh = r / 7, lw2 = r % 7;
  int d = (ld + 4) & 7;                       // shifted -> source coords
  int h = (hwin * 7 + lh + 3) % 56;
  int w = (wwin * 7 + lw2 + 3) % 56;
  size_t base = (size_t)b * 96 * SPAT + d * 3136 + h * 56 + w;
  int c = threadIdx.x;
  float v = (c < 96) ? x[base + (size_t)c * SPAT] : 0.f;
  s1[c] = v; s2[c] = v * v;
  __syncthreads();
  #pragma unroll
  for (int st = 64; st > 0; st >>= 1) {
    if (c < st) { s1[c] += s1[c + st]; s2[c] += s2[c + st]; }
    __syncthreads();
  }
  float mu = s1[0] * (1.f / 96.f);
  float var = s2[0] * (1.f / 96.f) - mu * mu;
  float rs = rsqrtf(var + 1e-5f);
  if (c < 96) xw[(size_t)t * 96 + c] = (v - mu) * rs * lw[c] + lb[c];
}

// ---------- kernel 2: qkv GEMM  (M=50176, K=96, N=288), out = A @ W^T + b ----------
__global__ __launch_bounds__(256)
void k_gemm_qkv(const float* __restrict__ A, const float* __restrict__ W,
                const float* __restrict__ bias, float* __restrict__ out) {
  __shared__ float As[16][100];
  __shared__ float Bs[16][100];
  int tx = threadIdx.x, ty = threadIdx.y;
  int n0 = blockIdx.x * 16, m0 = blockIdx.y * 16;
  #pragma unroll
  for (int k = 0; k < 96; k += 16) {
    As[ty][k + tx] = A[(size_t)(m0 + ty) * 96 + k + tx];
    Bs[ty][k + tx] = W[(size_t)(n0 + ty) * 96 + k + tx];
  }
  __syncthreads();
  float acc = 0.f;
  #pragma unroll 8
  for (int k = 0; k < 96; ++k) acc += As[ty][k] * Bs[tx][k];
  out[(size_t)(m0 + ty) * 288 + n0 + tx] = acc + bias[n0 + tx];
}

// ---------- kernel 3: window attention, one block per (window, head) ----------
template<int H, int DH>
__global__ __launch_bounds__(256)
void k_attn(const float* __restrict__ qkv, const float* __restrict__ rpb,
            float* __restrict__ out) {
  constexpr int RS = DH / 2 + 2;        // padded row stride in uints (bank spread, 8B align)
  constexpr int HP = DH / 2;            // data uints per row
  constexpr float SCALE = (DH == 32) ? 0.17677669529663689f : 0.25f;
  __shared__ __align__(16) unsigned int Ku[NTOK * RS];
  __shared__ __align__(16) unsigned int Vu[NTOK * RS];
  __shared__ float S[NTOK];
  __shared__ __align__(16) float Q[DH];
  __shared__ float redA[4], redB[4];
  __shared__ __align__(16) float red2[1024];
  __shared__ int RG[NTOK];

  int blk = blockIdx.x;
  int win = blk / H, head = blk % H;
  int wrem = win & 63;
  int hwin = wrem >> 3, wwin = wrem & 7;
  int tid = threadIdx.x;
  size_t wbase = (size_t)win * NTOK * 288;

  // stage K,V (bf16-packed) + region ids
  for (int u = tid; u < NTOK * HP; u += 256) {
    int j = u / HP, kk = u % HP;
    const float* src = qkv + wbase + (size_t)j * 288 + head * DH + 2 * kk;
    Ku[j * RS + kk] = pack2(src[96], src[97]);
    Vu[j * RS + kk] = pack2(src[192], src[193]);
  }
  for (int j = tid; j < NTOK; j += 256) {
    int ld = j / 49, r = j % 49, lh = r / 7, lw = r % 7;
    int hp = hwin * 7 + lh, wp = wwin * 7 + lw;
    int rd = (ld < 4) ? 1 : 2;
    int rh = (hp < 49) ? 0 : ((hp < 53) ? 1 : 2);
    int rw = (wp < 49) ? 0 : ((wp < 53) ? 1 : 2);
    RG[j] = rd * 9 + rh * 3 + rw;
  }
  __syncthreads();

  for (int i = 0; i < NTOK; ++i) {
    if (tid < DH) Q[tid] = qkv[wbase + (size_t)i * 288 + head * DH + tid];
    __syncthreads();
    float qr[DH];
    #pragma unroll
    for (int q4 = 0; q4 < DH / 4; ++q4) {
      float4 t4 = reinterpret_cast<const float4*>(Q)[q4];
      qr[4*q4] = t4.x; qr[4*q4+1] = t4.y; qr[4*q4+2] = t4.z; qr[4*q4+3] = t4.w;
    }
    int ldi = i / 49, ri = i % 49, lhi = ri / 7, lwi = ri % 7;
    int rgi = RG[i];
    float lmax = -1e30f;
    for (int j = tid; j < NTOK; j += 256) {
      float acc = 0.f;
      #pragma unroll
      for (int kq = 0; kq < DH / 4; ++kq) {
        uint2 u2 = *reinterpret_cast<const uint2*>(&Ku[j * RS + 2 * kq]);
        acc += qr[4*kq]   * bflo(u2.x) + qr[4*kq+1] * bfhi(u2.x)
             + qr[4*kq+2] * bflo(u2.y) + qr[4*kq+3] * bfhi(u2.y);
      }
      int ldj = j / 49, rj = j % 49, lhj = rj / 7, lwj = rj % 7;
      int rel = (ldi - ldj + 7) * 169 + (lhi - lhj + 6) * 13 + (lwi - lwj + 6);
      float sv = acc * SCALE + rpb[rel * H + head] + ((RG[j] != rgi) ? -100.f : 0.f);
      S[j] = sv;
      lmax = fmaxf(lmax, sv);
    }
    float bm = wmax64(lmax);
    if ((tid & 63) == 0) redA[tid >> 6] = bm;
    __syncthreads();                                  // also orders S writes -> reads
    float mx = fmaxf(fmaxf(redA[0], redA[1]), fmaxf(redA[2], redA[3]));
    float lsum = 0.f;
    for (int j = tid; j < NTOK; j += 256) {
      float p = expf(S[j] - mx);
      S[j] = p;
      lsum += p;
    }
    float bs = wsum64(lsum);
    if ((tid & 63) == 0) redB[tid >> 6] = bs;
    __syncthreads();                                  // orders p writes -> PV reads
    float inv = 1.f / (redB[0] + redB[1] + redB[2] + redB[3]);
    // PV: thread owns 4 d-channels (one uint2 column) over a j-chunk
    constexpr int HP2 = DH / 4;
    constexpr int NCH = 256 / HP2;
    constexpr int LEN = (NTOK + NCH - 1) / NCH;
    int chunk = tid / HP2, kk2 = tid % HP2;
    int j0 = chunk * LEN;
    int j1 = j0 + LEN; if (j1 > NTOK) j1 = NTOK;
    float a0 = 0.f, a1 = 0.f, a2 = 0.f, a3 = 0.f;
    for (int j = j0; j < j1; ++j) {
      uint2 u2 = *reinterpret_cast<const uint2*>(&Vu[j * RS + 2 * kk2]);
      float p = S[j];
      a0 += p * bflo(u2.x); a1 += p * bfhi(u2.x);
      a2 += p * bflo(u2.y); a3 += p * bfhi(u2.y);
    }
    reinterpret_cast<float4*>(red2)[tid] = make_float4(a0, a1, a2, a3);
    __syncthreads();
    if (tid < DH) {
      int g = tid >> 2, sub = tid & 3;
      float o = 0.f;
      #pragma unroll 8
      for (int c2 = 0; c2 < NCH; ++c2) o += red2[(c2 * HP2 + g) * 4 + sub];
      out[(size_t)(win * NTOK + i) * 96 + head * DH + tid] = o * inv;
    }
    __syncthreads();
  }
}

// ---------- kernel 4: proj x2 + alpha mix + window reverse + unshift + residual ----------
__global__ __launch_bounds__(128)
void k_proj(const float* __restrict__ ao0, const float* __restrict__ ao1,
            const float* __restrict__ pw0, const float* __restrict__ pb0,
            const float* __restrict__ pw1, const float* __restrict__ pb1,
            const float* __restrict__ alpha, const float* __restrict__ x,
            float* __restrict__ x1) {
  __shared__ float a0s[96], a1s[96];
  int t = blockIdx.x;
  int tid = threadIdx.x;
  if (tid < 96) {
    a0s[tid] = ao0[(size_t)t * 96 + tid];
    a1s[tid] = ao1[(size_t)t * 96 + tid];
  }
  __syncthreads();
  if (tid >= 96) return;
  float al0 = alpha[0], al1 = alpha[1];
  float m = fmaxf(al0, al1);
  float e0 = expf(al0 - m), e1 = expf(al1 - m);
  float aw0 = e0 / (e0 + e1), aw1 = e1 / (e0 + e1);
  float acc0 = pb0[tid], acc1 = pb1[tid];
  #pragma unroll 8
  for (int k = 0; k < 96; ++k) {
    acc0 += a0s[k] * pw0[tid * 96 + k];
    acc1 += a1s[k] * pw1[tid * 96 + k];
  }
  float val = aw0 * acc0 + aw1 * acc1;
  int win = t / NTOK, n = t % NTOK;
  int b = win >> 6, wrem = win & 63;
  int hwin = wrem >> 3, wwin = wrem & 7;
  int ld = n / 49, r = n % 49, lh = r / 7, lw = r % 7;
  int d = (ld + 4) & 7;                         // unshift (roll back +4,+3,+3)
  int h = (hwin * 7 + lh + 3) % 56;
  int w = (wwin * 7 + lw + 3) % 56;
  size_t idx = (size_t)(b * 96 + tid) * SPAT + d * 3136 + h * 56 + w;
  x1[idx] = x[idx] + val;
}

// ---------- kernel 5: LN2 (thread per spatial position) ----------
__global__ __launch_bounds__(256)
void k_ln2(const float* __restrict__ x1, const float* __restrict__ lw,
           const float* __restrict__ lb, float* __restrict__ x2) {
  int p = blockIdx.x * 256 + threadIdx.x;       // 0..50175
  int b = p / SPAT, s = p % SPAT;
  const float* xp = x1 + (size_t)b * 96 * SPAT + s;
  float sum = 0.f, sq = 0.f;
  #pragma unroll 8
  for (int c2 = 0; c2 < 96; ++c2) {
    float v = xp[(size_t)c2 * SPAT];
    sum += v; sq += v * v;
  }
  float mu = sum * (1.f / 96.f);
  float var = sq * (1.f / 96.f) - mu * mu;
  float rs = rsqrtf(var + 1e-5f);
  float* op = x2 + (size_t)b * 96 * SPAT + s;
  #pragma unroll 8
  for (int c2 = 0; c2 < 96; ++c2) {
    float v = xp[(size_t)c2 * SPAT];
    op[(size_t)c2 * SPAT] = (v - mu) * rs * lw[c2] + lb[c2];
  }
}

// ---------- kernel 6: FFN conv mixture + residual (in-place on d_out) ----------
__global__ __launch_bounds__(256)
void k_ffn(const float* __restrict__ x2,
           const float* __restrict__ c3w, const float* __restrict__ c3b,
           const float* __restrict__ c1w, const float* __restrict__ c1b,
           const float* __restrict__ dww, const float* __restrict__ dwb,
           const float* __restrict__ alpha, float* out) {
  int idx = blockIdx.x * 256 + threadIdx.x;
  if (idx >= NELEM) return;
  int w = idx % 56;
  int h = (idx / 56) % 56;
  int d = (idx / 3136) % 8;
  int co = (idx / SPAT) % 96;
  int b = idx / (SPAT * 96);
  float al0 = alpha[0], al1 = alpha[1], al2 = alpha[2], al3 = alpha[3];
  float mx = fmaxf(fmaxf(al0, al1), fmaxf(al2, al3));
  float e0 = expf(al0 - mx), e1 = expf(al1 - mx), e2 = expf(al2 - mx), e3 = expf(al3 - mx);
  float inv = 1.f / (e0 + e1 + e2 + e3);
  float f0 = e0 * inv, f1 = e1 * inv, f2 = e2 * inv, f3 = e3 * inv;
  const float* x2b = x2 + (size_t)b * 96 * SPAT;
  float acc3 = 0.f, accd = 0.f;
  #pragma unroll
  for (int kd = 0; kd < 3; ++kd) {
    int dz = d + kd - 1;
    if (dz < 0 || dz >= 8) continue;
    #pragma unroll
    for (int kh = 0; kh < 3; ++kh) {
      int hz = h + kh - 1;
      if (hz < 0 || hz >= 56) continue;
      #pragma unroll
      for (int kw = 0; kw < 3; ++kw) {
        int wz = w + kw - 1;
        if (wz < 0 || wz >= 56) continue;
        int sp = dz * 3136 + hz * 56 + wz;
        int ko = (kd * 3 + kh) * 3 + kw;
        accd += x2b[(size_t)co * SPAT + sp] * dww[co * 27 + ko];
        const float* xp = x2b + sp;
        const float* wp = c3w + (size_t)co * 96 * 27 + ko;
        float s = 0.f;
        #pragma unroll 4
        for (int ci = 0; ci < 96; ++ci) s += xp[(size_t)ci * SPAT] * wp[ci * 27];
        acc3 += s;
      }
    }
  }
  acc3 += c3b[co];
  accd += dwb[co];
  int sp0 = d * 3136 + h * 56 + w;
  float acc1 = c1b[co];
  const float* xp0 = x2b + sp0;
  #pragma unroll 8
  for (int ci = 0; ci < 96; ++ci) acc1 += xp0[(size_t)ci * SPAT] * c1w[co * 96 + ci];
  float idv = x2b[(size_t)co * SPAT + sp0];
  out[idx] = out[idx] + f0 * acc3 + f1 * acc1 + f2 * accd + f3 * idv;  // out holds x1
}

extern "C" void kernel_launch(void* const* d_in, const int* in_sizes, int n_in,
                              void* d_out, int out_size, void* d_ws, size_t ws_size,
                              hipStream_t stream) {
  (void)in_sizes; (void)n_in; (void)out_size; (void)ws_size;
  const float* x      = (const float*)d_in[0];
  const float* ln1w   = (const float*)d_in[1];
  const float* ln1b   = (const float*)d_in[2];
  const float* ln2w   = (const float*)d_in[3];
  const float* ln2b   = (const float*)d_in[4];
  const float* qkvw0  = (const float*)d_in[5];
  const float* qkvb0  = (const float*)d_in[6];
  const float* projw0 = (const float*)d_in[7];
  const float* projb0 = (const float*)d_in[8];
  const float* rpb0   = (const float*)d_in[9];
  const float* qkvw1  = (const float*)d_in[10];
  const float* qkvb1  = (const float*)d_in[11];
  const float* projw1 = (const float*)d_in[12];
  const float* projb1 = (const float*)d_in[13];
  const float* rpb1   = (const float*)d_in[14];
  const float* aattn  = (const float*)d_in[15];
  const float* c3w    = (const float*)d_in[16];
  const float* c3b    = (const float*)d_in[17];
  const float* c1w    = (const float*)d_in[18];
  const float* c1b    = (const float*)d_in[19];
  const float* dww    = (const float*)d_in[20];
  const float* dwb    = (const float*)d_in[21];
  const float* affn   = (const float*)d_in[22];

  // workspace layout (floats). Required: (3*4816896 + 14450688)*4 = 115.6 MB
  float* ws  = (float*)d_ws;
  float* xw  = ws;                      // tokens x 96 ; reused later as x2
  float* ao0 = ws + (size_t)NELEM;      // attn0 raw out, tokens x 96
  float* ao1 = ws + (size_t)2 * NELEM;  // attn1 raw out
  float* qkv = ws + (size_t)3 * NELEM;  // tokens x 288 (reused for both attns)
  float* x2  = xw;                      // alias: xw dead after 2nd qkv GEMM
  float* x1  = (float*)d_out;           // x1 lives in d_out

  k_ln1_win<<<NWIN * NTOK, 128, 0, stream>>>(x, ln1w, ln1b, xw);
  k_gemm_qkv<<<dim3(18, 3136), dim3(16, 16), 0, stream>>>(xw, qkvw0, qkvb0, qkv);
  k_attn<3, 32><<<NWIN * 3, 256, 0, stream>>>(qkv, rpb0, ao0);
  k_gemm_qkv<<<dim3(18, 3136), dim3(16, 16), 0, stream>>>(xw, qkvw1, qkvb1, qkv);
  k_attn<6, 16><<<NWIN * 6, 256, 0, stream>>>(qkv, rpb1, ao1);
  k_proj<<<NWIN * NTOK, 128, 0, stream>>>(ao0, ao1, projw0, projb0, projw1, projb1,
                                          aattn, x, x1);
  k_ln2<<<196, 256, 0, stream>>>(x1, ln2w, ln2b, x2);
  k_ffn<<<(NELEM + 255) / 256, 256, 0, stream>>>(x2, c3w, c3b, c1w, c1b, dww, dwb,
                                                 affn, (float*)d_out);
}

// Round 2
// 3128.080 us; speedup vs baseline: 2.2881x; 2.2881x over previous
//
#include <hip/hip_runtime.h>

#define NWIN 128       // B * nW windows
#define NTOK 392       // tokens per window (8*7*7)
#define SPAT 25088     // D*H*W
#define NELEM 4816896  // 2*96*25088

typedef unsigned short u16t;
typedef unsigned int u32t;
typedef __attribute__((ext_vector_type(8))) short short8;
typedef __attribute__((ext_vector_type(4))) float f32x4;

// xpad geometry: [b][ci][10][58][58] bf16, zero border
#define PW 58
#define PHW 3364      // 58*58
#define PSPAT 33640   // 10*58*58
#define XPAD_U16 6458880   // 2*96*33640
#define WCOMB_N 248832     // 27*96*96

// ---------- helpers ----------
__device__ __forceinline__ unsigned int f2bf(float f) {
  unsigned int u = __float_as_uint(f);
  return (u + 0x7fffu + ((u >> 16) & 1u)) >> 16;   // RNE to bf16
}
__device__ __forceinline__ unsigned int pack2(float a, float b) {
  return f2bf(a) | (f2bf(b) << 16);
}
__device__ __forceinline__ float bflo(unsigned int u) { return __uint_as_float(u << 16); }
__device__ __forceinline__ float bfhi(unsigned int u) { return __uint_as_float(u & 0xffff0000u); }

__device__ __forceinline__ float wmax64(float v) {
  #pragma unroll
  for (int o = 32; o > 0; o >>= 1) v = fmaxf(v, __shfl_xor(v, o, 64));
  return v;
}
__device__ __forceinline__ float wsum64(float v) {
  #pragma unroll
  for (int o = 32; o > 0; o >>= 1) v += __shfl_xor(v, o, 64);
  return v;
}

// ---------- kernel 1: LN1 over C + roll(-4,-3,-3) + window partition ----------
__global__ __launch_bounds__(128)
void k_ln1_win(const float* __restrict__ x, const float* __restrict__ lw,
               const float* __restrict__ lb, float* __restrict__ xw) {
  __shared__ float s1[128], s2[128];
  int t = blockIdx.x;                 // destination token
  int win = t / NTOK, n = t % NTOK;
  int b = win >> 6, wrem = win & 63;
  int hwin = wrem >> 3, wwin = wrem & 7;
  int ld = n / 49, r = n % 49, lh = r / 7, lw2 = r % 7;
  int d = (ld + 4) & 7;                       // shifted -> source coords
  int h = (hwin * 7 + lh + 3) % 56;
  int w = (wwin * 7 + lw2 + 3) % 56;
  size_t base = (size_t)b * 96 * SPAT + d * 3136 + h * 56 + w;
  int c = threadIdx.x;
  float v = (c < 96) ? x[base + (size_t)c * SPAT] : 0.f;
  s1[c] = v; s2[c] = v * v;
  __syncthreads();
  #pragma unroll
  for (int st = 64; st > 0; st >>= 1) {
    if (c < st) { s1[c] += s1[c + st]; s2[c] += s2[c + st]; }
    __syncthreads();
  }
  float mu = s1[0] * (1.f / 96.f);
  float var = s2[0] * (1.f / 96.f) - mu * mu;
  float rs = rsqrtf(var + 1e-5f);
  if (c < 96) xw[(size_t)t * 96 + c] = (v - mu) * rs * lw[c] + lb[c];
}

// ---------- kernel 2: qkv GEMM  (M=50176, K=96, N=288), out = A @ W^T + b ----------
__global__ __launch_bounds__(256)
void k_gemm_qkv(const float* __restrict__ A, const float* __restrict__ W,
                const float* __restrict__ bias, float* __restrict__ out) {
  __shared__ float As[16][100];
  __shared__ float Bs[16][100];
  int tx = threadIdx.x, ty = threadIdx.y;
  int n0 = blockIdx.x * 16, m0 = blockIdx.y * 16;
  #pragma unroll
  for (int k = 0; k < 96; k += 16) {
    As[ty][k + tx] = A[(size_t)(m0 + ty) * 96 + k + tx];
    Bs[ty][k + tx] = W[(size_t)(n0 + ty) * 96 + k + tx];
  }
  __syncthreads();
  float acc = 0.f;
  #pragma unroll 8
  for (int k = 0; k < 96; ++k) acc += As[ty][k] * Bs[tx][k];
  out[(size_t)(m0 + ty) * 288 + n0 + tx] = acc + bias[n0 + tx];
}

// ---------- kernel 3: window attention, one block per (window, head) ----------
template<int H, int DH>
__global__ __launch_bounds__(256)
void k_attn(const float* __restrict__ qkv, const float* __restrict__ rpb,
            float* __restrict__ out) {
  constexpr int RS = DH / 2 + 2;        // padded row stride in uints
  constexpr int HP = DH / 2;            // data uints per row
  constexpr float SCALE = (DH == 32) ? 0.17677669529663689f : 0.25f;
  __shared__ __align__(16) unsigned int Ku[NTOK * RS];
  __shared__ __align__(16) unsigned int Vu[NTOK * RS];
  __shared__ float S[NTOK];
  __shared__ __align__(16) float Q[DH];
  __shared__ float redA[4], redB[4];
  __shared__ __align__(16) float red2[1024];
  __shared__ int RG[NTOK];

  int blk = blockIdx.x;
  int win = blk / H, head = blk % H;
  int wrem = win & 63;
  int hwin = wrem >> 3, wwin = wrem & 7;
  int tid = threadIdx.x;
  size_t wbase = (size_t)win * NTOK * 288;

  for (int u = tid; u < NTOK * HP; u += 256) {
    int j = u / HP, kk = u % HP;
    const float* src = qkv + wbase + (size_t)j * 288 + head * DH + 2 * kk;
    Ku[j * RS + kk] = pack2(src[96], src[97]);
    Vu[j * RS + kk] = pack2(src[192], src[193]);
  }
  for (int j = tid; j < NTOK; j += 256) {
    int ld = j / 49, r = j % 49, lh = r / 7, lw = r % 7;
    int hp = hwin * 7 + lh, wp = wwin * 7 + lw;
    int rd = (ld < 4) ? 1 : 2;
    int rh = (hp < 49) ? 0 : ((hp < 53) ? 1 : 2);
    int rw = (wp < 49) ? 0 : ((wp < 53) ? 1 : 2);
    RG[j] = rd * 9 + rh * 3 + rw;
  }
  __syncthreads();

  for (int i = 0; i < NTOK; ++i) {
    if (tid < DH) Q[tid] = qkv[wbase + (size_t)i * 288 + head * DH + tid];
    __syncthreads();
    float qr[DH];
    #pragma unroll
    for (int q4 = 0; q4 < DH / 4; ++q4) {
      float4 t4 = reinterpret_cast<const float4*>(Q)[q4];
      qr[4*q4] = t4.x; qr[4*q4+1] = t4.y; qr[4*q4+2] = t4.z; qr[4*q4+3] = t4.w;
    }
    int ldi = i / 49, ri = i % 49, lhi = ri / 7, lwi = ri % 7;
    int rgi = RG[i];
    float lmax = -1e30f;
    for (int j = tid; j < NTOK; j += 256) {
      float acc = 0.f;
      #pragma unroll
      for (int kq = 0; kq < DH / 4; ++kq) {
        uint2 u2 = *reinterpret_cast<const uint2*>(&Ku[j * RS + 2 * kq]);
        acc += qr[4*kq]   * bflo(u2.x) + qr[4*kq+1] * bfhi(u2.x)
             + qr[4*kq+2] * bflo(u2.y) + qr[4*kq+3] * bfhi(u2.y);
      }
      int ldj = j / 49, rj = j % 49, lhj = rj / 7, lwj = rj % 7;
      int rel = (ldi - ldj + 7) * 169 + (lhi - lhj + 6) * 13 + (lwi - lwj + 6);
      float sv = acc * SCALE + rpb[rel * H + head] + ((RG[j] != rgi) ? -100.f : 0.f);
      S[j] = sv;
      lmax = fmaxf(lmax, sv);
    }
    float bm = wmax64(lmax);
    if ((tid & 63) == 0) redA[tid >> 6] = bm;
    __syncthreads();
    float mx = fmaxf(fmaxf(redA[0], redA[1]), fmaxf(redA[2], redA[3]));
    float lsum = 0.f;
    for (int j = tid; j < NTOK; j += 256) {
      float p = expf(S[j] - mx);
      S[j] = p;
      lsum += p;
    }
    float bs = wsum64(lsum);
    if ((tid & 63) == 0) redB[tid >> 6] = bs;
    __syncthreads();
    float inv = 1.f / (redB[0] + redB[1] + redB[2] + redB[3]);
    constexpr int HP2 = DH / 4;
    constexpr int NCH = 256 / HP2;
    constexpr int LEN = (NTOK + NCH - 1) / NCH;
    int chunk = tid / HP2, kk2 = tid % HP2;
    int j0 = chunk * LEN;
    int j1 = j0 + LEN; if (j1 > NTOK) j1 = NTOK;
    float a0 = 0.f, a1 = 0.f, a2 = 0.f, a3 = 0.f;
    for (int j = j0; j < j1; ++j) {
      uint2 u2 = *reinterpret_cast<const uint2*>(&Vu[j * RS + 2 * kk2]);
      float p = S[j];
      a0 += p * bflo(u2.x); a1 += p * bfhi(u2.x);
      a2 += p * bflo(u2.y); a3 += p * bfhi(u2.y);
    }
    reinterpret_cast<float4*>(red2)[tid] = make_float4(a0, a1, a2, a3);
    __syncthreads();
    if (tid < DH) {
      int g = tid >> 2, sub = tid & 3;
      float o = 0.f;
      #pragma unroll 8
      for (int c2 = 0; c2 < NCH; ++c2) o += red2[(c2 * HP2 + g) * 4 + sub];
      out[(size_t)(win * NTOK + i) * 96 + head * DH + tid] = o * inv;
    }
    __syncthreads();
  }
}

// ---------- kernel 4: proj x2 + alpha mix + window reverse + unshift + residual ----------
__global__ __launch_bounds__(128)
void k_proj(const float* __restrict__ ao0, const float* __restrict__ ao1,
            const float* __restrict__ pw0, const float* __restrict__ pb0,
            const float* __restrict__ pw1, const float* __restrict__ pb1,
            const float* __restrict__ alpha, const float* __restrict__ x,
            float* __restrict__ x1) {
  __shared__ float a0s[96], a1s[96];
  int t = blockIdx.x;
  int tid = threadIdx.x;
  if (tid < 96) {
    a0s[tid] = ao0[(size_t)t * 96 + tid];
    a1s[tid] = ao1[(size_t)t * 96 + tid];
  }
  __syncthreads();
  if (tid >= 96) return;
  float al0 = alpha[0], al1 = alpha[1];
  float m = fmaxf(al0, al1);
  float e0 = expf(al0 - m), e1 = expf(al1 - m);
  float aw0 = e0 / (e0 + e1), aw1 = e1 / (e0 + e1);
  float acc0 = pb0[tid], acc1 = pb1[tid];
  #pragma unroll 8
  for (int k = 0; k < 96; ++k) {
    acc0 += a0s[k] * pw0[tid * 96 + k];
    acc1 += a1s[k] * pw1[tid * 96 + k];
  }
  float val = aw0 * acc0 + aw1 * acc1;
  int win = t / NTOK, n = t % NTOK;
  int b = win >> 6, wrem = win & 63;
  int hwin = wrem >> 3, wwin = wrem & 7;
  int ld = n / 49, r = n % 49, lh = r / 7, lw = r % 7;
  int d = (ld + 4) & 7;
  int h = (hwin * 7 + lh + 3) % 56;
  int w = (wwin * 7 + lw + 3) % 56;
  size_t idx = (size_t)(b * 96 + tid) * SPAT + d * 3136 + h * 56 + w;
  x1[idx] = x[idx] + val;
}

// ---------- kernel 5a: zero xpad ----------
__global__ __launch_bounds__(256)
void k_zero(uint4* __restrict__ p, int n) {
  int i = blockIdx.x * 256 + threadIdx.x;
  if (i < n) p[i] = make_uint4(0u, 0u, 0u, 0u);
}

// ---------- kernel 5b: combined FFN weights (softmax-alpha folded), bf16 ----------
__global__ __launch_bounds__(256)
void k_wprep(const float* __restrict__ c3w, const float* __restrict__ c3b,
             const float* __restrict__ c1w, const float* __restrict__ c1b,
             const float* __restrict__ dww, const float* __restrict__ dwb,
             const float* __restrict__ alpha,
             u16t* __restrict__ wcomb, float* __restrict__ bcomb) {
  int e = blockIdx.x * 256 + threadIdx.x;
  if (e >= WCOMB_N) return;
  float a0 = alpha[0], a1 = alpha[1], a2 = alpha[2], a3 = alpha[3];
  float mx = fmaxf(fmaxf(a0, a1), fmaxf(a2, a3));
  float e0 = expf(a0 - mx), e1 = expf(a1 - mx), e2 = expf(a2 - mx), e3 = expf(a3 - mx);
  float inv = 1.f / (e0 + e1 + e2 + e3);
  float f0 = e0 * inv, f1 = e1 * inv, f2 = e2 * inv, f3 = e3 * inv;
  int ko = e / 9216, rm = e % 9216, co = rm / 96, ci = rm % 96;
  float v = f0 * c3w[(co * 96 + ci) * 27 + ko];
  if (ko == 13) v += f1 * c1w[co * 96 + ci];
  if (ci == co) v += f2 * dww[co * 27 + ko];
  if (ko == 13 && ci == co) v += f3;
  wcomb[e] = (u16t)f2bf(v);
  if (e < 96) bcomb[e] = f0 * c3b[e] + f1 * c1b[e] + f2 * dwb[e];
}

// ---------- kernel 5c: LN2 -> padded bf16 tensor ----------
__global__ __launch_bounds__(256)
void k_ln2pad(const float* __restrict__ x1, const float* __restrict__ lw,
              const float* __restrict__ lb, u16t* __restrict__ xpad) {
  int p = blockIdx.x * 256 + threadIdx.x;       // 0..50175
  int b = p / SPAT, s = p % SPAT;
  int d = s / 3136, r = s % 3136, h = r / 56, w = r % 56;
  const float* xp = x1 + (size_t)b * 96 * SPAT + s;
  float sum = 0.f, sq = 0.f;
  #pragma unroll 8
  for (int c = 0; c < 96; ++c) {
    float v = xp[(size_t)c * SPAT];
    sum += v; sq += v * v;
  }
  float mu = sum * (1.f / 96.f);
  float var = sq * (1.f / 96.f) - mu * mu;
  float rs = rsqrtf(var + 1e-5f);
  u16t* op = xpad + (size_t)b * 96 * PSPAT + (d + 1) * PHW + (h + 1) * PW + (w + 1);
  #pragma unroll 8
  for (int c = 0; c < 96; ++c) {
    float v = xp[(size_t)c * SPAT];
    op[(size_t)c * PSPAT] = (u16t)f2bf((v - mu) * rs * lw[c] + lb[c]);
  }
}

// ---------- kernel 6: FFN implicit GEMM via MFMA ----------
// One wave per block. M = 96 co (6 frags), N = 16 spatial, K = 96ci x 27ko.
// A = combined weights [co][ci] per ko (16B contiguous loads),
// B = xpad [ci][pos+delta] (8 strided u16 loads/lane, coalesced across lanes).
__global__ __launch_bounds__(64)
void k_ffn_mfma(const u16t* __restrict__ xpad, const u16t* __restrict__ wcomb,
                const float* __restrict__ bcomb, float* __restrict__ out) {
  int lane = threadIdx.x;
  int arow = lane & 15;        // A row (co%16) AND B col (spatial)
  int kg = lane >> 4;          // k-group of 8
  int m = blockIdx.x * 16 + arow;            // spatial output id
  int b = m / SPAT, r = m % SPAT;
  int d = r / 3136, r2 = r % 3136, h = r2 / 56, w = r2 % 56;
  int pbase = b * (96 * PSPAT) + d * PHW + h * PW + w + kg * 8 * PSPAT;
  int obase = b * (96 * SPAT) + r;
  int abase = arow * 96 + kg * 8;

  f32x4 acc[6];
  #pragma unroll
  for (int f = 0; f < 6; ++f) acc[f] = (f32x4){0.f, 0.f, 0.f, 0.f};

  for (int ko = 0; ko < 27; ++ko) {
    int kd = ko / 9, kh = (ko / 3) % 3, kw = ko % 3;
    int bofs = pbase + kd * PHW + kh * PW + kw;
    const u16t* wko = wcomb + ko * 9216 + abase;
    #pragma unroll
    for (int cc = 0; cc < 3; ++cc) {
      const u16t* bp = xpad + bofs + cc * 32 * PSPAT;
      u32t uu[8];
      #pragma unroll
      for (int i = 0; i < 8; ++i) uu[i] = bp[i * PSPAT];
      union { u32t u[4]; short8 v; } bu;
      #pragma unroll
      for (int j = 0; j < 4; ++j) bu.u[j] = uu[2 * j] | (uu[2 * j + 1] << 16);
      const u16t* ap = wko + cc * 32;
      #pragma unroll
      for (int f = 0; f < 6; ++f) {
        short8 av = *reinterpret_cast<const short8*>(ap + f * 1536);
        acc[f] = __builtin_amdgcn_mfma_f32_16x16x32_bf16(av, bu.v, acc[f], 0, 0, 0);
      }
    }
  }
  // epilogue: D col = lane&15 = spatial, row = kg*4+j = co%16 ; residual RMW on x1
  #pragma unroll
  for (int f = 0; f < 6; ++f) {
    #pragma unroll
    for (int j = 0; j < 4; ++j) {
      int co = f * 16 + kg * 4 + j;
      float* o = out + obase + co * SPAT;
      *o = *o + acc[f][j] + bcomb[co];
    }
  }
}

extern "C" void kernel_launch(void* const* d_in, const int* in_sizes, int n_in,
                              void* d_out, int out_size, void* d_ws, size_t ws_size,
                              hipStream_t stream) {
  (void)in_sizes; (void)n_in; (void)out_size; (void)ws_size;
  const float* x      = (const float*)d_in[0];
  const float* ln1w   = (const float*)d_in[1];
  const float* ln1b   = (const float*)d_in[2];
  const float* ln2w   = (const float*)d_in[3];
  const float* ln2b   = (const float*)d_in[4];
  const float* qkvw0  = (const float*)d_in[5];
  const float* qkvb0  = (const float*)d_in[6];
  const float* projw0 = (const float*)d_in[7];
  const float* projb0 = (const float*)d_in[8];
  const float* rpb0   = (const float*)d_in[9];
  const float* qkvw1  = (const float*)d_in[10];
  const float* qkvb1  = (const float*)d_in[11];
  const float* projw1 = (const float*)d_in[12];
  const float* projb1 = (const float*)d_in[13];
  const float* rpb1   = (const float*)d_in[14];
  const float* aattn  = (const float*)d_in[15];
  const float* c3w    = (const float*)d_in[16];
  const float* c3b    = (const float*)d_in[17];
  const float* c1w    = (const float*)d_in[18];
  const float* c1b    = (const float*)d_in[19];
  const float* dww    = (const float*)d_in[20];
  const float* dwb    = (const float*)d_in[21];
  const float* affn   = (const float*)d_in[22];

  // workspace: [xw | ao0 | ao1 | qkv-region]; qkv region reused for xpad/wcomb/bcomb
  float* ws  = (float*)d_ws;
  float* xw  = ws;
  float* ao0 = ws + (size_t)NELEM;
  float* ao1 = ws + (size_t)2 * NELEM;
  float* qkv = ws + (size_t)3 * NELEM;       // tokens x 288 (both attns)
  u16t* xpad  = (u16t*)qkv;                  // 12.9 MB, overlaps dead qkv
  u16t* wcomb = xpad + XPAD_U16;             // 0.5 MB
  float* bcomb = (float*)(wcomb + WCOMB_N);  // 96 floats
  float* x1  = (float*)d_out;

  k_ln1_win<<<NWIN * NTOK, 128, 0, stream>>>(x, ln1w, ln1b, xw);
  k_gemm_qkv<<<dim3(18, 3136), dim3(16, 16), 0, stream>>>(xw, qkvw0, qkvb0, qkv);
  k_attn<3, 32><<<NWIN * 3, 256, 0, stream>>>(qkv, rpb0, ao0);
  k_gemm_qkv<<<dim3(18, 3136), dim3(16, 16), 0, stream>>>(xw, qkvw1, qkvb1, qkv);
  k_attn<6, 16><<<NWIN * 6, 256, 0, stream>>>(qkv, rpb1, ao1);
  // qkv now dead: build xpad / combined weights in its place
  k_zero<<<(XPAD_U16 / 8 + 255) / 256, 256, 0, stream>>>((uint4*)xpad, XPAD_U16 / 8);
  k_wprep<<<(WCOMB_N + 255) / 256, 256, 0, stream>>>(c3w, c3b, c1w, c1b, dww, dwb,
                                                     affn, wcomb, bcomb);
  k_proj<<<NWIN * NTOK, 128, 0, stream>>>(ao0, ao1, projw0, projb0, projw1, projb1,
                                          aattn, x, x1);
  k_ln2pad<<<196, 256, 0, stream>>>(x1, ln2w, ln2b, xpad);
  k_ffn_mfma<<<3136, 64, 0, stream>>>(xpad, wcomb, bcomb, (float*)d_out);
}

// Round 3
// 1177.225 us; speedup vs baseline: 6.0800x; 2.6572x over previous
//
#include <hip/hip_runtime.h>

#define NWIN 128       // B * nW windows
#define NTOK 392       // tokens per window (8*7*7)
#define SPAT 25088     // D*H*W
#define NELEM 4816896  // 2*96*25088

typedef unsigned short u16t;
typedef unsigned int u32t;
typedef __attribute__((ext_vector_type(8))) short short8;
typedef __attribute__((ext_vector_type(4))) float f32x4;

// xpad geometry: [b][ci][10][58][58] bf16, zero border
#define PW 58
#define PHW 3364      // 58*58
#define PSPAT 33640   // 10*58*58
#define XPAD_U16 6458880   // 2*96*33640
#define WCOMB_N 248832     // 27*96*96

// ---------- helpers ----------
__device__ __forceinline__ unsigned int f2bf(float f) {
  unsigned int u = __float_as_uint(f);
  return (u + 0x7fffu + ((u >> 16) & 1u)) >> 16;   // RNE to bf16
}
__device__ __forceinline__ unsigned int pack2(float a, float b) {
  return f2bf(a) | (f2bf(b) << 16);
}

// ---------- kernel 1: LN1 over C + roll(-4,-3,-3) + window partition ----------
__global__ __launch_bounds__(128)
void k_ln1_win(const float* __restrict__ x, const float* __restrict__ lw,
               const float* __restrict__ lb, float* __restrict__ xw) {
  __shared__ float s1[128], s2[128];
  int t = blockIdx.x;                 // destination token
  int win = t / NTOK, n = t % NTOK;
  int b = win >> 6, wrem = win & 63;
  int hwin = wrem >> 3, wwin = wrem & 7;
  int ld = n / 49, r = n % 49, lh = r / 7, lw2 = r % 7;
  int d = (ld + 4) & 7;                       // shifted -> source coords
  int h = (hwin * 7 + lh + 3) % 56;
  int w = (wwin * 7 + lw2 + 3) % 56;
  size_t base = (size_t)b * 96 * SPAT + d * 3136 + h * 56 + w;
  int c = threadIdx.x;
  float v = (c < 96) ? x[base + (size_t)c * SPAT] : 0.f;
  s1[c] = v; s2[c] = v * v;
  __syncthreads();
  #pragma unroll
  for (int st = 64; st > 0; st >>= 1) {
    if (c < st) { s1[c] += s1[c + st]; s2[c] += s2[c + st]; }
    __syncthreads();
  }
  float mu = s1[0] * (1.f / 96.f);
  float var = s2[0] * (1.f / 96.f) - mu * mu;
  float rs = rsqrtf(var + 1e-5f);
  if (c < 96) xw[(size_t)t * 96 + c] = (v - mu) * rs * lw[c] + lb[c];
}

// ---------- kernel 2: qkv GEMM  (M=50176, K=96, N=288), out = A @ W^T + b ----------
__global__ __launch_bounds__(256)
void k_gemm_qkv(const float* __restrict__ A, const float* __restrict__ W,
                const float* __restrict__ bias, float* __restrict__ out) {
  __shared__ float As[16][100];
  __shared__ float Bs[16][100];
  int tx = threadIdx.x, ty = threadIdx.y;
  int n0 = blockIdx.x * 16, m0 = blockIdx.y * 16;
  #pragma unroll
  for (int k = 0; k < 96; k += 16) {
    As[ty][k + tx] = A[(size_t)(m0 + ty) * 96 + k + tx];
    Bs[ty][k + tx] = W[(size_t)(n0 + ty) * 96 + k + tx];
  }
  __syncthreads();
  float acc = 0.f;
  #pragma unroll 8
  for (int k = 0; k < 96; ++k) acc += As[ty][k] * Bs[tx][k];
  out[(size_t)(m0 + ty) * 288 + n0 + tx] = acc + bias[n0 + tx];
}

// ---------- kernel 3: MFMA window attention ----------
// Block = (window, head), 4 waves. Swapped QK^T (S^T = K.Q^T) so softmax is
// lane-local + 2 shfl_xor. P kept in registers; PV via shuffle-built A-frags.
template<int H, int DH>
__global__ __launch_bounds__(256)
void k_attn_mfma(const float* __restrict__ qkv, const float* __restrict__ rpb,
                 float* __restrict__ out) {
  constexpr float SCALE = (DH == 32) ? 0.17677669529663689f : 0.25f;
  constexpr int NT = DH / 16;  // output dh-tiles
  __shared__ __align__(16) u16t Ks[400 * 32];    // [tok][32] XOR-swizzled chunks
  __shared__ __align__(16) u16t VTs[32 * 408];   // [dh][tok], stride 408
  __shared__ float rpbs[2535];
  __shared__ int Ts[400];
  __shared__ int RGs[400];

  int blk = blockIdx.x;
  int win = blk / H, head = blk % H;
  int wrem = win & 63;
  int hwin = wrem >> 3, wwin = wrem & 7;
  int tid = threadIdx.x;
  int lane = tid & 63, wv = tid >> 6;
  int c = lane & 15, lg = lane >> 4;
  size_t wbase = (size_t)win * NTOK * 288;

  {  // zero Ks, VTs (pads must be 0; garbage NaN would poison mfma)
    uint4 z = make_uint4(0u, 0u, 0u, 0u);
    uint4* k4 = (uint4*)Ks;
    for (int i = tid; i < 1600; i += 256) k4[i] = z;
    uint4* v4 = (uint4*)VTs;
    for (int i = tid; i < 1632; i += 256) v4[i] = z;
  }
  __syncthreads();
  for (int u = tid; u < NTOK * DH; u += 256) {
    int j = u / DH, d = u % DH;
    float kvf = qkv[wbase + (size_t)j * 288 + 96 + head * DH + d];
    float vvf = qkv[wbase + (size_t)j * 288 + 192 + head * DH + d];
    int schunk = (d >> 3) ^ (j & 3);
    Ks[j * 32 + schunk * 8 + (d & 7)] = (u16t)f2bf(kvf);
    VTs[d * 408 + j] = (u16t)f2bf(vvf);
  }
  for (int i = tid; i < 2535; i += 256) rpbs[i] = rpb[i * H + head];
  for (int j = tid; j < 400; j += 256) {
    if (j < NTOK) {
      int ld = j / 49, r = j % 49, lh = r / 7, lw = r % 7;
      Ts[j] = ld * 169 + lh * 13 + lw;
      int hp = hwin * 7 + lh, wp = wwin * 7 + lw;
      int rd = (ld < 4) ? 1 : 2;
      int rh = (hp < 49) ? 0 : ((hp < 53) ? 1 : 2);
      int rw = (wp < 49) ? 0 : ((wp < 53) ? 1 : 2);
      RGs[j] = rd * 9 + rh * 3 + rw;
    } else { Ts[j] = 0; RGs[j] = 255; }
  }
  __syncthreads();

  for (int qt = wv; qt < 25; qt += 4) {
    int qtok = qt * 16 + c;
    int qcl = (qtok < NTOK) ? qtok : NTOK - 1;
    int Tq = Ts[qcl], rgq = RGs[qcl];
    // Q B-frag: B[kdim][q] = Q[q][dh], contiguous 8 floats -> bf16x8
    short8 bq;
    {
      float qf[8];
      const float* qp = qkv + wbase + (size_t)qcl * 288 + head * DH;
      #pragma unroll
      for (int e = 0; e < 8; ++e)
        qf[e] = (DH == 32 || lg < 2) ? qp[lg * 8 + e] : 0.f;
      union { u32t u[4]; short8 v; } bu;
      #pragma unroll
      for (int i2 = 0; i2 < 4; ++i2) bu.u[i2] = pack2(qf[2 * i2], qf[2 * i2 + 1]);
      bq = bu.v;
    }
    f32x4 p[26];
    p[25] = (f32x4){0.f, 0.f, 0.f, 0.f};   // virtual zero tile for odd pairing
    float lmax = -1e30f;
    #pragma unroll
    for (int t = 0; t < 25; ++t) {
      short8 av = *reinterpret_cast<const short8*>(
          &Ks[(16 * t + c) * 32 + ((lg ^ (c & 3)) * 8)]);
      f32x4 acc = (f32x4){0.f, 0.f, 0.f, 0.f};
      acc = __builtin_amdgcn_mfma_f32_16x16x32_bf16(av, bq, acc, 0, 0, 0);
      #pragma unroll
      for (int j = 0; j < 4; ++j) {
        int k = 16 * t + lg * 4 + j;
        float sv = acc[j] * SCALE + rpbs[Tq - Ts[k] + 1267]
                 + ((RGs[k] != rgq) ? -100.f : 0.f);
        if (k >= NTOK) sv = -1e30f;        // only possible at t==24, folds away
        p[t][j] = sv;
        lmax = fmaxf(lmax, sv);
      }
    }
    lmax = fmaxf(lmax, __shfl_xor(lmax, 16));
    lmax = fmaxf(lmax, __shfl_xor(lmax, 32));
    float lsum = 0.f;
    #pragma unroll
    for (int t = 0; t < 25; ++t) {
      #pragma unroll
      for (int j = 0; j < 4; ++j) {
        float e = __expf(p[t][j] - lmax);
        p[t][j] = e;
        lsum += e;
      }
    }
    lsum += __shfl_xor(lsum, 16);
    lsum += __shfl_xor(lsum, 32);
    float inv = 1.f / lsum;
    // PV: out = P.V ; A-frags from p via pack + cross-lane exchange
    f32x4 oacc[NT];
    #pragma unroll
    for (int ot = 0; ot < NT; ++ot) oacc[ot] = (f32x4){0.f, 0.f, 0.f, 0.f};
    int srcl = ((lane >> 4) & 1) * 32 + c;
    #pragma unroll
    for (int s = 0; s < 13; ++s) {
      u32t pk0x = pack2(p[2 * s][0], p[2 * s][1]);
      u32t pk0y = pack2(p[2 * s][2], p[2 * s][3]);
      u32t pk1x = pack2(p[2 * s + 1][0], p[2 * s + 1][1]);
      u32t pk1y = pack2(p[2 * s + 1][2], p[2 * s + 1][3]);
      u32t ax = (u32t)__shfl((int)pk0x, srcl),      ay = (u32t)__shfl((int)pk0y, srcl);
      u32t bx = (u32t)__shfl((int)pk0x, srcl + 16), by = (u32t)__shfl((int)pk0y, srcl + 16);
      u32t cx = (u32t)__shfl((int)pk1x, srcl),      cy = (u32t)__shfl((int)pk1y, srcl);
      u32t dx = (u32t)__shfl((int)pk1x, srcl + 16), dy = (u32t)__shfl((int)pk1y, srcl + 16);
      bool hi = (lane & 32) != 0;
      union { u32t u[4]; short8 v; } au;
      au.u[0] = hi ? cx : ax; au.u[1] = hi ? cy : ay;
      au.u[2] = hi ? dx : bx; au.u[3] = hi ? dy : by;
      #pragma unroll
      for (int ot = 0; ot < NT; ++ot) {
        short8 bv = *reinterpret_cast<const short8*>(
            &VTs[(ot * 16 + c) * 408 + 32 * s + lg * 8]);
        oacc[ot] = __builtin_amdgcn_mfma_f32_16x16x32_bf16(au.v, bv, oacc[ot], 0, 0, 0);
      }
    }
    float invj[4];
    #pragma unroll
    for (int j = 0; j < 4; ++j) invj[j] = __shfl(inv, lg * 4 + j);
    #pragma unroll
    for (int j = 0; j < 4; ++j) {
      int q = qt * 16 + lg * 4 + j;
      if (q < NTOK) {
        #pragma unroll
        for (int ot = 0; ot < NT; ++ot)
          out[(size_t)(win * NTOK + q) * 96 + head * DH + ot * 16 + c] =
              oacc[ot][j] * invj[j];
      }
    }
  }
}

// ---------- kernel 4: proj x2 + alpha mix + window reverse + unshift + residual ----------
__global__ __launch_bounds__(128)
void k_proj(const float* __restrict__ ao0, const float* __restrict__ ao1,
            const float* __restrict__ pw0, const float* __restrict__ pb0,
            const float* __restrict__ pw1, const float* __restrict__ pb1,
            const float* __restrict__ alpha, const float* __restrict__ x,
            float* __restrict__ x1) {
  __shared__ float a0s[96], a1s[96];
  int t = blockIdx.x;
  int tid = threadIdx.x;
  if (tid < 96) {
    a0s[tid] = ao0[(size_t)t * 96 + tid];
    a1s[tid] = ao1[(size_t)t * 96 + tid];
  }
  __syncthreads();
  if (tid >= 96) return;
  float al0 = alpha[0], al1 = alpha[1];
  float m = fmaxf(al0, al1);
  float e0 = expf(al0 - m), e1 = expf(al1 - m);
  float aw0 = e0 / (e0 + e1), aw1 = e1 / (e0 + e1);
  float acc0 = pb0[tid], acc1 = pb1[tid];
  #pragma unroll 8
  for (int k = 0; k < 96; ++k) {
    acc0 += a0s[k] * pw0[tid * 96 + k];
    acc1 += a1s[k] * pw1[tid * 96 + k];
  }
  float val = aw0 * acc0 + aw1 * acc1;
  int win = t / NTOK, n = t % NTOK;
  int b = win >> 6, wrem = win & 63;
  int hwin = wrem >> 3, wwin = wrem & 7;
  int ld = n / 49, r = n % 49, lh = r / 7, lw = r % 7;
  int d = (ld + 4) & 7;
  int h = (hwin * 7 + lh + 3) % 56;
  int w = (wwin * 7 + lw + 3) % 56;
  size_t idx = (size_t)(b * 96 + tid) * SPAT + d * 3136 + h * 56 + w;
  x1[idx] = x[idx] + val;
}

// ---------- kernel 5a: zero xpad ----------
__global__ __launch_bounds__(256)
void k_zero(uint4* __restrict__ p, int n) {
  int i = blockIdx.x * 256 + threadIdx.x;
  if (i < n) p[i] = make_uint4(0u, 0u, 0u, 0u);
}

// ---------- kernel 5b: combined FFN weights (softmax-alpha folded), bf16 ----------
__global__ __launch_bounds__(256)
void k_wprep(const float* __restrict__ c3w, const float* __restrict__ c3b,
             const float* __restrict__ c1w, const float* __restrict__ c1b,
             const float* __restrict__ dww, const float* __restrict__ dwb,
             const float* __restrict__ alpha,
             u16t* __restrict__ wcomb, float* __restrict__ bcomb) {
  int e = blockIdx.x * 256 + threadIdx.x;
  if (e >= WCOMB_N) return;
  float a0 = alpha[0], a1 = alpha[1], a2 = alpha[2], a3 = alpha[3];
  float mx = fmaxf(fmaxf(a0, a1), fmaxf(a2, a3));
  float e0 = expf(a0 - mx), e1 = expf(a1 - mx), e2 = expf(a2 - mx), e3 = expf(a3 - mx);
  float inv = 1.f / (e0 + e1 + e2 + e3);
  float f0 = e0 * inv, f1 = e1 * inv, f2 = e2 * inv, f3 = e3 * inv;
  int ko = e / 9216, rm = e % 9216, co = rm / 96, ci = rm % 96;
  float v = f0 * c3w[(co * 96 + ci) * 27 + ko];
  if (ko == 13) v += f1 * c1w[co * 96 + ci];
  if (ci == co) v += f2 * dww[co * 27 + ko];
  if (ko == 13 && ci == co) v += f3;
  wcomb[e] = (u16t)f2bf(v);
  if (e < 96) bcomb[e] = f0 * c3b[e] + f1 * c1b[e] + f2 * dwb[e];
}

// ---------- kernel 5c: LN2 -> padded bf16 tensor ----------
__global__ __launch_bounds__(256)
void k_ln2pad(const float* __restrict__ x1, const float* __restrict__ lw,
              const float* __restrict__ lb, u16t* __restrict__ xpad) {
  int p = blockIdx.x * 256 + threadIdx.x;       // 0..50175
  int b = p / SPAT, s = p % SPAT;
  int d = s / 3136, r = s % 3136, h = r / 56, w = r % 56;
  const float* xp = x1 + (size_t)b * 96 * SPAT + s;
  float sum = 0.f, sq = 0.f;
  #pragma unroll 8
  for (int c = 0; c < 96; ++c) {
    float v = xp[(size_t)c * SPAT];
    sum += v; sq += v * v;
  }
  float mu = sum * (1.f / 96.f);
  float var = sq * (1.f / 96.f) - mu * mu;
  float rs = rsqrtf(var + 1e-5f);
  u16t* op = xpad + (size_t)b * 96 * PSPAT + (d + 1) * PHW + (h + 1) * PW + (w + 1);
  #pragma unroll 8
  for (int c = 0; c < 96; ++c) {
    float v = xp[(size_t)c * SPAT];
    op[(size_t)c * PSPAT] = (u16t)f2bf((v - mu) * rs * lw[c] + lb[c]);
  }
}

// ---------- kernel 6: FFN implicit GEMM via MFMA ----------
__global__ __launch_bounds__(64)
void k_ffn_mfma(const u16t* __restrict__ xpad, const u16t* __restrict__ wcomb,
                const float* __restrict__ bcomb, float* __restrict__ out) {
  int lane = threadIdx.x;
  int arow = lane & 15;
  int kg = lane >> 4;
  int m = blockIdx.x * 16 + arow;
  int b = m / SPAT, r = m % SPAT;
  int d = r / 3136, r2 = r % 3136, h = r2 / 56, w = r2 % 56;
  int pbase = b * (96 * PSPAT) + d * PHW + h * PW + w + kg * 8 * PSPAT;
  int obase = b * (96 * SPAT) + r;
  int abase = arow * 96 + kg * 8;

  f32x4 acc[6];
  #pragma unroll
  for (int f = 0; f < 6; ++f) acc[f] = (f32x4){0.f, 0.f, 0.f, 0.f};

  for (int ko = 0; ko < 27; ++ko) {
    int kd = ko / 9, kh = (ko / 3) % 3, kw = ko % 3;
    int bofs = pbase + kd * PHW + kh * PW + kw;
    const u16t* wko = wcomb + ko * 9216 + abase;
    #pragma unroll
    for (int cc = 0; cc < 3; ++cc) {
      const u16t* bp = xpad + bofs + cc * 32 * PSPAT;
      u32t uu[8];
      #pragma unroll
      for (int i = 0; i < 8; ++i) uu[i] = bp[i * PSPAT];
      union { u32t u[4]; short8 v; } bu;
      #pragma unroll
      for (int j = 0; j < 4; ++j) bu.u[j] = uu[2 * j] | (uu[2 * j + 1] << 16);
      const u16t* ap = wko + cc * 32;
      #pragma unroll
      for (int f = 0; f < 6; ++f) {
        short8 av = *reinterpret_cast<const short8*>(ap + f * 1536);
        acc[f] = __builtin_amdgcn_mfma_f32_16x16x32_bf16(av, bu.v, acc[f], 0, 0, 0);
      }
    }
  }
  #pragma unroll
  for (int f = 0; f < 6; ++f) {
    #pragma unroll
    for (int j = 0; j < 4; ++j) {
      int co = f * 16 + kg * 4 + j;
      float* o = out + obase + co * SPAT;
      *o = *o + acc[f][j] + bcomb[co];
    }
  }
}

extern "C" void kernel_launch(void* const* d_in, const int* in_sizes, int n_in,
                              void* d_out, int out_size, void* d_ws, size_t ws_size,
                              hipStream_t stream) {
  (void)in_sizes; (void)n_in; (void)out_size; (void)ws_size;
  const float* x      = (const float*)d_in[0];
  const float* ln1w   = (const float*)d_in[1];
  const float* ln1b   = (const float*)d_in[2];
  const float* ln2w   = (const float*)d_in[3];
  const float* ln2b   = (const float*)d_in[4];
  const float* qkvw0  = (const float*)d_in[5];
  const float* qkvb0  = (const float*)d_in[6];
  const float* projw0 = (const float*)d_in[7];
  const float* projb0 = (const float*)d_in[8];
  const float* rpb0   = (const float*)d_in[9];
  const float* qkvw1  = (const float*)d_in[10];
  const float* qkvb1  = (const float*)d_in[11];
  const float* projw1 = (const float*)d_in[12];
  const float* projb1 = (const float*)d_in[13];
  const float* rpb1   = (const float*)d_in[14];
  const float* aattn  = (const float*)d_in[15];
  const float* c3w    = (const float*)d_in[16];
  const float* c3b    = (const float*)d_in[17];
  const float* c1w    = (const float*)d_in[18];
  const float* c1b    = (const float*)d_in[19];
  const float* dww    = (const float*)d_in[20];
  const float* dwb    = (const float*)d_in[21];
  const float* affn   = (const float*)d_in[22];

  float* ws  = (float*)d_ws;
  float* xw  = ws;
  float* ao0 = ws + (size_t)NELEM;
  float* ao1 = ws + (size_t)2 * NELEM;
  float* qkv = ws + (size_t)3 * NELEM;
  u16t* xpad  = (u16t*)qkv;
  u16t* wcomb = xpad + XPAD_U16;
  float* bcomb = (float*)(wcomb + WCOMB_N);
  float* x1  = (float*)d_out;

  k_ln1_win<<<NWIN * NTOK, 128, 0, stream>>>(x, ln1w, ln1b, xw);
  k_gemm_qkv<<<dim3(18, 3136), dim3(16, 16), 0, stream>>>(xw, qkvw0, qkvb0, qkv);
  k_attn_mfma<3, 32><<<NWIN * 3, 256, 0, stream>>>(qkv, rpb0, ao0);
  k_gemm_qkv<<<dim3(18, 3136), dim3(16, 16), 0, stream>>>(xw, qkvw1, qkvb1, qkv);
  k_attn_mfma<6, 16><<<NWIN * 6, 256, 0, stream>>>(qkv, rpb1, ao1);
  k_zero<<<(XPAD_U16 / 8 + 255) / 256, 256, 0, stream>>>((uint4*)xpad, XPAD_U16 / 8);
  k_wprep<<<(WCOMB_N + 255) / 256, 256, 0, stream>>>(c3w, c3b, c1w, c1b, dww, dwb,
                                                     affn, wcomb, bcomb);
  k_proj<<<NWIN * NTOK, 128, 0, stream>>>(ao0, ao1, projw0, projb0, projw1, projb1,
                                          aattn, x, x1);
  k_ln2pad<<<196, 256, 0, stream>>>(x1, ln2w, ln2b, xpad);
  k_ffn_mfma<<<3136, 64, 0, stream>>>(xpad, wcomb, bcomb, (float*)d_out);
}

// Round 4
// 735.690 us; speedup vs baseline: 9.7290x; 1.6002x over previous
//
#include <hip/hip_runtime.h>

#define NWIN 128       // B * nW windows
#define NTOK 392       // tokens per window (8*7*7)
#define SPAT 25088     // D*H*W
#define NELEM 4816896  // 2*96*25088

typedef unsigned short u16t;
typedef unsigned int u32t;
typedef __attribute__((ext_vector_type(8))) short short8;
typedef __attribute__((ext_vector_type(4))) float f32x4;

// xpad geometry: [b][ci][10][58][58] bf16, zero border
#define PW 58
#define PHW 3364      // 58*58
#define PSPAT 33640   // 10*58*58
#define XPAD_U16 6458880   // 2*96*33640
#define WCOMB_N 248832     // 27*96*96
#define WPROJ_N 18432      // 96*192

// ---------- helpers ----------
__device__ __forceinline__ unsigned int f2bf(float f) {
  unsigned int u = __float_as_uint(f);
  return (u + 0x7fffu + ((u >> 16) & 1u)) >> 16;   // RNE to bf16
}
__device__ __forceinline__ unsigned int pack2(float a, float b) {
  return f2bf(a) | (f2bf(b) << 16);
}

// ---------- kernel 1: LN1 over C + roll(-4,-3,-3) + window partition ----------
__global__ __launch_bounds__(128)
void k_ln1_win(const float* __restrict__ x, const float* __restrict__ lw,
               const float* __restrict__ lb, float* __restrict__ xw) {
  __shared__ float s1[128], s2[128];
  int t = blockIdx.x;                 // destination token
  int win = t / NTOK, n = t % NTOK;
  int b = win >> 6, wrem = win & 63;
  int hwin = wrem >> 3, wwin = wrem & 7;
  int ld = n / 49, r = n % 49, lh = r / 7, lw2 = r % 7;
  int d = (ld + 4) & 7;                       // shifted -> source coords
  int h = (hwin * 7 + lh + 3) % 56;
  int w = (wwin * 7 + lw2 + 3) % 56;
  size_t base = (size_t)b * 96 * SPAT + d * 3136 + h * 56 + w;
  int c = threadIdx.x;
  float v = (c < 96) ? x[base + (size_t)c * SPAT] : 0.f;
  s1[c] = v; s2[c] = v * v;
  __syncthreads();
  #pragma unroll
  for (int st = 64; st > 0; st >>= 1) {
    if (c < st) { s1[c] += s1[c + st]; s2[c] += s2[c + st]; }
    __syncthreads();
  }
  float mu = s1[0] * (1.f / 96.f);
  float var = s2[0] * (1.f / 96.f) - mu * mu;
  float rs = rsqrtf(var + 1e-5f);
  if (c < 96) xw[(size_t)t * 96 + c] = (v - mu) * rs * lw[c] + lb[c];
}

// ---------- kernel 2: qkv GEMM  (M=50176, K=96, N=288), out = A @ W^T + b ----------
__global__ __launch_bounds__(256)
void k_gemm_qkv(const float* __restrict__ A, const float* __restrict__ W,
                const float* __restrict__ bias, float* __restrict__ out) {
  __shared__ float As[16][100];
  __shared__ float Bs[16][100];
  int tx = threadIdx.x, ty = threadIdx.y;
  int n0 = blockIdx.x * 16, m0 = blockIdx.y * 16;
  #pragma unroll
  for (int k = 0; k < 96; k += 16) {
    As[ty][k + tx] = A[(size_t)(m0 + ty) * 96 + k + tx];
    Bs[ty][k + tx] = W[(size_t)(n0 + ty) * 96 + k + tx];
  }
  __syncthreads();
  float acc = 0.f;
  #pragma unroll 8
  for (int k = 0; k < 96; ++k) acc += As[ty][k] * Bs[tx][k];
  out[(size_t)(m0 + ty) * 288 + n0 + tx] = acc + bias[n0 + tx];
}

// ---------- kernel 3: MFMA window attention (bf16 output into combined buffer) ----------
template<int H, int DH>
__global__ __launch_bounds__(256)
void k_attn_mfma(const float* __restrict__ qkv, const float* __restrict__ rpb,
                 u16t* __restrict__ aot) {
  constexpr float SCALE = (DH == 32) ? 0.17677669529663689f : 0.25f;
  constexpr int NT = DH / 16;  // output dh-tiles
  __shared__ __align__(16) u16t Ks[400 * 32];    // [tok][32] XOR-swizzled chunks
  __shared__ __align__(16) u16t VTs[32 * 408];   // [dh][tok], stride 408
  __shared__ float rpbs[2535];
  __shared__ int Ts[400];
  __shared__ int RGs[400];

  int blk = blockIdx.x;
  int win = blk / H, head = blk % H;
  int wrem = win & 63;
  int hwin = wrem >> 3, wwin = wrem & 7;
  int tid = threadIdx.x;
  int lane = tid & 63, wv = tid >> 6;
  int c = lane & 15, lg = lane >> 4;
  size_t wbase = (size_t)win * NTOK * 288;
  int hoff = (DH == 32) ? head * 32 : 96 + head * 16;   // column base in aot

  {  // zero Ks, VTs (pads must be 0)
    uint4 z = make_uint4(0u, 0u, 0u, 0u);
    uint4* k4 = (uint4*)Ks;
    for (int i = tid; i < 1600; i += 256) k4[i] = z;
    uint4* v4 = (uint4*)VTs;
    for (int i = tid; i < 1632; i += 256) v4[i] = z;
  }
  __syncthreads();
  for (int u = tid; u < NTOK * DH; u += 256) {
    int j = u / DH, d = u % DH;
    float kvf = qkv[wbase + (size_t)j * 288 + 96 + head * DH + d];
    float vvf = qkv[wbase + (size_t)j * 288 + 192 + head * DH + d];
    int schunk = (d >> 3) ^ (j & 3);
    Ks[j * 32 + schunk * 8 + (d & 7)] = (u16t)f2bf(kvf);
    VTs[d * 408 + j] = (u16t)f2bf(vvf);
  }
  for (int i = tid; i < 2535; i += 256) rpbs[i] = rpb[i * H + head];
  for (int j = tid; j < 400; j += 256) {
    if (j < NTOK) {
      int ld = j / 49, r = j % 49, lh = r / 7, lw = r % 7;
      Ts[j] = ld * 169 + lh * 13 + lw;
      int hp = hwin * 7 + lh, wp = wwin * 7 + lw;
      int rd = (ld < 4) ? 1 : 2;
      int rh = (hp < 49) ? 0 : ((hp < 53) ? 1 : 2);
      int rw = (wp < 49) ? 0 : ((wp < 53) ? 1 : 2);
      RGs[j] = rd * 9 + rh * 3 + rw;
    } else { Ts[j] = 0; RGs[j] = 255; }
  }
  __syncthreads();

  for (int qt = wv; qt < 25; qt += 4) {
    int qtok = qt * 16 + c;
    int qcl = (qtok < NTOK) ? qtok : NTOK - 1;
    int Tq = Ts[qcl], rgq = RGs[qcl];
    short8 bq;
    {
      float qf[8];
      const float* qp = qkv + wbase + (size_t)qcl * 288 + head * DH;
      #pragma unroll
      for (int e = 0; e < 8; ++e)
        qf[e] = (DH == 32 || lg < 2) ? qp[lg * 8 + e] : 0.f;
      union { u32t u[4]; short8 v; } bu;
      #pragma unroll
      for (int i2 = 0; i2 < 4; ++i2) bu.u[i2] = pack2(qf[2 * i2], qf[2 * i2 + 1]);
      bq = bu.v;
    }
    f32x4 p[26];
    p[25] = (f32x4){0.f, 0.f, 0.f, 0.f};
    float lmax = -1e30f;
    #pragma unroll
    for (int t = 0; t < 25; ++t) {
      short8 av = *reinterpret_cast<const short8*>(
          &Ks[(16 * t + c) * 32 + ((lg ^ (c & 3)) * 8)]);
      f32x4 acc = (f32x4){0.f, 0.f, 0.f, 0.f};
      acc = __builtin_amdgcn_mfma_f32_16x16x32_bf16(av, bq, acc, 0, 0, 0);
      #pragma unroll
      for (int j = 0; j < 4; ++j) {
        int k = 16 * t + lg * 4 + j;
        float sv = acc[j] * SCALE + rpbs[Tq - Ts[k] + 1267]
                 + ((RGs[k] != rgq) ? -100.f : 0.f);
        if (k >= NTOK) sv = -1e30f;
        p[t][j] = sv;
        lmax = fmaxf(lmax, sv);
      }
    }
    lmax = fmaxf(lmax, __shfl_xor(lmax, 16));
    lmax = fmaxf(lmax, __shfl_xor(lmax, 32));
    float lsum = 0.f;
    #pragma unroll
    for (int t = 0; t < 25; ++t) {
      #pragma unroll
      for (int j = 0; j < 4; ++j) {
        float e = __expf(p[t][j] - lmax);
        p[t][j] = e;
        lsum += e;
      }
    }
    lsum += __shfl_xor(lsum, 16);
    lsum += __shfl_xor(lsum, 32);
    float inv = 1.f / lsum;
    f32x4 oacc[NT];
    #pragma unroll
    for (int ot = 0; ot < NT; ++ot) oacc[ot] = (f32x4){0.f, 0.f, 0.f, 0.f};
    int srcl = ((lane >> 4) & 1) * 32 + c;
    #pragma unroll
    for (int s = 0; s < 13; ++s) {
      u32t pk0x = pack2(p[2 * s][0], p[2 * s][1]);
      u32t pk0y = pack2(p[2 * s][2], p[2 * s][3]);
      u32t pk1x = pack2(p[2 * s + 1][0], p[2 * s + 1][1]);
      u32t pk1y = pack2(p[2 * s + 1][2], p[2 * s + 1][3]);
      u32t ax = (u32t)__shfl((int)pk0x, srcl),      ay = (u32t)__shfl((int)pk0y, srcl);
      u32t bx = (u32t)__shfl((int)pk0x, srcl + 16), by = (u32t)__shfl((int)pk0y, srcl + 16);
      u32t cx = (u32t)__shfl((int)pk1x, srcl),      cy = (u32t)__shfl((int)pk1y, srcl);
      u32t dx = (u32t)__shfl((int)pk1x, srcl + 16), dy = (u32t)__shfl((int)pk1y, srcl + 16);
      bool hi = (lane & 32) != 0;
      union { u32t u[4]; short8 v; } au;
      au.u[0] = hi ? cx : ax; au.u[1] = hi ? cy : ay;
      au.u[2] = hi ? dx : bx; au.u[3] = hi ? dy : by;
      #pragma unroll
      for (int ot = 0; ot < NT; ++ot) {
        short8 bv = *reinterpret_cast<const short8*>(
            &VTs[(ot * 16 + c) * 408 + 32 * s + lg * 8]);
        oacc[ot] = __builtin_amdgcn_mfma_f32_16x16x32_bf16(au.v, bv, oacc[ot], 0, 0, 0);
      }
    }
    float invj[4];
    #pragma unroll
    for (int j = 0; j < 4; ++j) invj[j] = __shfl(inv, lg * 4 + j);
    #pragma unroll
    for (int j = 0; j < 4; ++j) {
      int q = qt * 16 + lg * 4 + j;
      if (q < NTOK) {
        #pragma unroll
        for (int ot = 0; ot < NT; ++ot)
          aot[(size_t)(win * NTOK + q) * 192 + hoff + ot * 16 + c] =
              (u16t)f2bf(oacc[ot][j] * invj[j]);
      }
    }
  }
}

// ---------- kernel 4a: combined proj weights (alpha folded), bf16 ----------
__global__ __launch_bounds__(256)
void k_pprep(const float* __restrict__ pw0, const float* __restrict__ pb0,
             const float* __restrict__ pw1, const float* __restrict__ pb1,
             const float* __restrict__ alpha,
             u16t* __restrict__ wp, float* __restrict__ bp) {
  int e = blockIdx.x * 256 + threadIdx.x;
  if (e >= WPROJ_N) return;
  float al0 = alpha[0], al1 = alpha[1];
  float m = fmaxf(al0, al1);
  float e0 = expf(al0 - m), e1 = expf(al1 - m);
  float aw0 = e0 / (e0 + e1), aw1 = e1 / (e0 + e1);
  int co = e / 192, k = e % 192;
  float v = (k < 96) ? aw0 * pw0[co * 96 + k] : aw1 * pw1[co * 96 + k - 96];
  wp[e] = (u16t)f2bf(v);
  if (e < 96) bp[e] = aw0 * pb0[e] + aw1 * pb1[e];
}

// ---------- kernel 4b: proj via MFMA + window reverse + unshift + residual ----------
// One wave/block: 16 tokens x 96 co, K=192.
__global__ __launch_bounds__(64)
void k_proj_mfma(const u16t* __restrict__ aot, const u16t* __restrict__ wp,
                 const float* __restrict__ bp, const float* __restrict__ x,
                 float* __restrict__ x1) {
  int lane = threadIdx.x;
  int c = lane & 15, lg = lane >> 4;
  int t = blockIdx.x * 16 + c;
  int win = t / NTOK, n = t % NTOK;
  int b = win >> 6, wrem = win & 63;
  int hwin = wrem >> 3, wwin = wrem & 7;
  int ld = n / 49, r = n % 49, lh = r / 7, lw = r % 7;
  int d = (ld + 4) & 7;
  int h = (hwin * 7 + lh + 3) % 56;
  int w = (wwin * 7 + lw + 3) % 56;
  size_t base = (size_t)b * 96 * SPAT + d * 3136 + h * 56 + w;

  const u16t* ap = aot + (size_t)t * 192 + lg * 8;
  f32x4 acc[6];
  #pragma unroll
  for (int f = 0; f < 6; ++f) acc[f] = (f32x4){0.f, 0.f, 0.f, 0.f};
  #pragma unroll
  for (int kc = 0; kc < 6; ++kc) {
    short8 bv = *reinterpret_cast<const short8*>(ap + kc * 32);
    #pragma unroll
    for (int f = 0; f < 6; ++f) {
      short8 av = *reinterpret_cast<const short8*>(wp + (f * 16 + c) * 192 + kc * 32 + lg * 8);
      acc[f] = __builtin_amdgcn_mfma_f32_16x16x32_bf16(av, bv, acc[f], 0, 0, 0);
    }
  }
  #pragma unroll
  for (int f = 0; f < 6; ++f) {
    #pragma unroll
    for (int j = 0; j < 4; ++j) {
      int co = f * 16 + lg * 4 + j;
      size_t idx = base + (size_t)co * SPAT;
      x1[idx] = x[idx] + acc[f][j] + bp[co];
    }
  }
}

// ---------- kernel 5a: zero xpad ----------
__global__ __launch_bounds__(256)
void k_zero(uint4* __restrict__ p, int n) {
  int i = blockIdx.x * 256 + threadIdx.x;
  if (i < n) p[i] = make_uint4(0u, 0u, 0u, 0u);
}

// ---------- kernel 5b: combined FFN weights (softmax-alpha folded), bf16 ----------
__global__ __launch_bounds__(256)
void k_wprep(const float* __restrict__ c3w, const float* __restrict__ c3b,
             const float* __restrict__ c1w, const float* __restrict__ c1b,
             const float* __restrict__ dww, const float* __restrict__ dwb,
             const float* __restrict__ alpha,
             u16t* __restrict__ wcomb, float* __restrict__ bcomb) {
  int e = blockIdx.x * 256 + threadIdx.x;
  if (e >= WCOMB_N) return;
  float a0 = alpha[0], a1 = alpha[1], a2 = alpha[2], a3 = alpha[3];
  float mx = fmaxf(fmaxf(a0, a1), fmaxf(a2, a3));
  float e0 = expf(a0 - mx), e1 = expf(a1 - mx), e2 = expf(a2 - mx), e3 = expf(a3 - mx);
  float inv = 1.f / (e0 + e1 + e2 + e3);
  float f0 = e0 * inv, f1 = e1 * inv, f2 = e2 * inv, f3 = e3 * inv;
  int ko = e / 9216, rm = e % 9216, co = rm / 96, ci = rm % 96;
  float v = f0 * c3w[(co * 96 + ci) * 27 + ko];
  if (ko == 13) v += f1 * c1w[co * 96 + ci];
  if (ci == co) v += f2 * dww[co * 27 + ko];
  if (ko == 13 && ci == co) v += f3;
  wcomb[e] = (u16t)f2bf(v);
  if (e < 96) bcomb[e] = f0 * c3b[e] + f1 * c1b[e] + f2 * dwb[e];
}

// ---------- kernel 5c: LN2 -> padded bf16 tensor ----------
__global__ __launch_bounds__(256)
void k_ln2pad(const float* __restrict__ x1, const float* __restrict__ lw,
              const float* __restrict__ lb, u16t* __restrict__ xpad) {
  int p = blockIdx.x * 256 + threadIdx.x;       // 0..50175
  int b = p / SPAT, s = p % SPAT;
  int d = s / 3136, r = s % 3136, h = r / 56, w = r % 56;
  const float* xp = x1 + (size_t)b * 96 * SPAT + s;
  float sum = 0.f, sq = 0.f;
  #pragma unroll 8
  for (int c = 0; c < 96; ++c) {
    float v = xp[(size_t)c * SPAT];
    sum += v; sq += v * v;
  }
  float mu = sum * (1.f / 96.f);
  float var = sq * (1.f / 96.f) - mu * mu;
  float rs = rsqrtf(var + 1e-5f);
  u16t* op = xpad + (size_t)b * 96 * PSPAT + (d + 1) * PHW + (h + 1) * PW + (w + 1);
  #pragma unroll 8
  for (int c = 0; c < 96; ++c) {
    float v = xp[(size_t)c * SPAT];
    op[(size_t)c * PSPAT] = (u16t)f2bf((v - mu) * rs * lw[c] + lb[c]);
  }
}

// ---------- kernel 6: FFN implicit GEMM via MFMA ----------
__global__ __launch_bounds__(64)
void k_ffn_mfma(const u16t* __restrict__ xpad, const u16t* __restrict__ wcomb,
                const float* __restrict__ bcomb, float* __restrict__ out) {
  int lane = threadIdx.x;
  int arow = lane & 15;
  int kg = lane >> 4;
  int m = blockIdx.x * 16 + arow;
  int b = m / SPAT, r = m % SPAT;
  int d = r / 3136, r2 = r % 3136, h = r2 / 56, w = r2 % 56;
  int pbase = b * (96 * PSPAT) + d * PHW + h * PW + w + kg * 8 * PSPAT;
  int obase = b * (96 * SPAT) + r;
  int abase = arow * 96 + kg * 8;

  f32x4 acc[6];
  #pragma unroll
  for (int f = 0; f < 6; ++f) acc[f] = (f32x4){0.f, 0.f, 0.f, 0.f};

  for (int ko = 0; ko < 27; ++ko) {
    int kd = ko / 9, kh = (ko / 3) % 3, kw = ko % 3;
    int bofs = pbase + kd * PHW + kh * PW + kw;
    const u16t* wko = wcomb + ko * 9216 + abase;
    #pragma unroll
    for (int cc = 0; cc < 3; ++cc) {
      const u16t* bp = xpad + bofs + cc * 32 * PSPAT;
      u32t uu[8];
      #pragma unroll
      for (int i = 0; i < 8; ++i) uu[i] = bp[i * PSPAT];
      union { u32t u[4]; short8 v; } bu;
      #pragma unroll
      for (int j = 0; j < 4; ++j) bu.u[j] = uu[2 * j] | (uu[2 * j + 1] << 16);
      const u16t* ap = wko + cc * 32;
      #pragma unroll
      for (int f = 0; f < 6; ++f) {
        short8 av = *reinterpret_cast<const short8*>(ap + f * 1536);
        acc[f] = __builtin_amdgcn_mfma_f32_16x16x32_bf16(av, bu.v, acc[f], 0, 0, 0);
      }
    }
  }
  #pragma unroll
  for (int f = 0; f < 6; ++f) {
    #pragma unroll
    for (int j = 0; j < 4; ++j) {
      int co = f * 16 + kg * 4 + j;
      float* o = out + obase + co * SPAT;
      *o = *o + acc[f][j] + bcomb[co];
    }
  }
}

extern "C" void kernel_launch(void* const* d_in, const int* in_sizes, int n_in,
                              void* d_out, int out_size, void* d_ws, size_t ws_size,
                              hipStream_t stream) {
  (void)in_sizes; (void)n_in; (void)out_size; (void)ws_size;
  const float* x      = (const float*)d_in[0];
  const float* ln1w   = (const float*)d_in[1];
  const float* ln1b   = (const float*)d_in[2];
  const float* ln2w   = (const float*)d_in[3];
  const float* ln2b   = (const float*)d_in[4];
  const float* qkvw0  = (const float*)d_in[5];
  const float* qkvb0  = (const float*)d_in[6];
  const float* projw0 = (const float*)d_in[7];
  const float* projb0 = (const float*)d_in[8];
  const float* rpb0   = (const float*)d_in[9];
  const float* qkvw1  = (const float*)d_in[10];
  const float* qkvb1  = (const float*)d_in[11];
  const float* projw1 = (const float*)d_in[12];
  const float* projb1 = (const float*)d_in[13];
  const float* rpb1   = (const float*)d_in[14];
  const float* aattn  = (const float*)d_in[15];
  const float* c3w    = (const float*)d_in[16];
  const float* c3b    = (const float*)d_in[17];
  const float* c1w    = (const float*)d_in[18];
  const float* c1b    = (const float*)d_in[19];
  const float* dww    = (const float*)d_in[20];
  const float* dwb    = (const float*)d_in[21];
  const float* affn   = (const float*)d_in[22];

  // workspace: [xw f32 | aot u16(=NELEM f32) | qkv-region f32]
  float* ws  = (float*)d_ws;
  float* xw  = ws;
  u16t*  aot = (u16t*)(ws + (size_t)NELEM);      // [50176][192] bf16
  float* qkv = ws + (size_t)2 * NELEM;           // tokens x 288 (both attns)
  u16t* xpad  = (u16t*)qkv;                      // reuses dead qkv region
  u16t* wcomb = xpad + XPAD_U16;
  float* bcomb = (float*)(wcomb + WCOMB_N);
  u16t* wproj = (u16t*)(bcomb + 96);
  float* bproj = (float*)(wproj + WPROJ_N);
  float* x1  = (float*)d_out;

  k_ln1_win<<<NWIN * NTOK, 128, 0, stream>>>(x, ln1w, ln1b, xw);
  k_gemm_qkv<<<dim3(18, 3136), dim3(16, 16), 0, stream>>>(xw, qkvw0, qkvb0, qkv);
  k_attn_mfma<3, 32><<<NWIN * 3, 256, 0, stream>>>(qkv, rpb0, aot);
  k_gemm_qkv<<<dim3(18, 3136), dim3(16, 16), 0, stream>>>(xw, qkvw1, qkvb1, qkv);
  k_attn_mfma<6, 16><<<NWIN * 6, 256, 0, stream>>>(qkv, rpb1, aot);
  // qkv dead: build xpad / combined weights in its place
  k_zero<<<(XPAD_U16 / 8 + 255) / 256, 256, 0, stream>>>((uint4*)xpad, XPAD_U16 / 8);
  k_wprep<<<(WCOMB_N + 255) / 256, 256, 0, stream>>>(c3w, c3b, c1w, c1b, dww, dwb,
                                                     affn, wcomb, bcomb);
  k_pprep<<<(WPROJ_N + 255) / 256, 256, 0, stream>>>(projw0, projb0, projw1, projb1,
                                                     aattn, wproj, bproj);
  k_proj_mfma<<<3136, 64, 0, stream>>>(aot, wproj, bproj, x, x1);
  k_ln2pad<<<196, 256, 0, stream>>>(x1, ln2w, ln2b, xpad);
  k_ffn_mfma<<<3136, 64, 0, stream>>>(xpad, wcomb, bcomb, (float*)d_out);
}

// Round 5
// 527.195 us; speedup vs baseline: 13.5766x; 1.3955x over previous
//
#include <hip/hip_runtime.h>

#define NWIN 128       // B * nW windows
#define NTOK 392       // tokens per window (8*7*7)
#define SPAT 25088     // D*H*W
#define NELEM 4816896  // 2*96*25088

typedef unsigned short u16t;
typedef unsigned int u32t;
typedef __attribute__((ext_vector_type(8))) short short8;
typedef __attribute__((ext_vector_type(4))) float f32x4;

// xpad geometry: [b][ci][10][58][58] bf16, zero border
#define PW 58
#define PHW 3364      // 58*58
#define PSPAT 33640   // 10*58*58
#define XPAD_U16 6458880   // 2*96*33640
#define WCOMB_N 248832     // 27*96*96
#define WPROJ_N 18432      // 96*192
#define NTOKTOT 50176      // NWIN*NTOK

// ---------- helpers ----------
__device__ __forceinline__ unsigned int f2bf(float f) {
  unsigned int u = __float_as_uint(f);
  return (u + 0x7fffu + ((u >> 16) & 1u)) >> 16;   // RNE to bf16
}
__device__ __forceinline__ unsigned int pack2(float a, float b) {
  return f2bf(a) | (f2bf(b) << 16);
}

// ---------- kernel 1: LN1 over C + roll(-4,-3,-3) + window partition (bf16 out) ----------
__global__ __launch_bounds__(128)
void k_ln1_win(const float* __restrict__ x, const float* __restrict__ lw,
               const float* __restrict__ lb, u16t* __restrict__ xw) {
  __shared__ float s1[128], s2[128];
  int t = blockIdx.x;                 // destination token
  int win = t / NTOK, n = t % NTOK;
  int b = win >> 6, wrem = win & 63;
  int hwin = wrem >> 3, wwin = wrem & 7;
  int ld = n / 49, r = n % 49, lh = r / 7, lw2 = r % 7;
  int d = (ld + 4) & 7;                       // shifted -> source coords
  int h = (hwin * 7 + lh + 3) % 56;
  int w = (wwin * 7 + lw2 + 3) % 56;
  size_t base = (size_t)b * 96 * SPAT + d * 3136 + h * 56 + w;
  int c = threadIdx.x;
  float v = (c < 96) ? x[base + (size_t)c * SPAT] : 0.f;
  s1[c] = v; s2[c] = v * v;
  __syncthreads();
  #pragma unroll
  for (int st = 64; st > 0; st >>= 1) {
    if (c < st) { s1[c] += s1[c + st]; s2[c] += s2[c + st]; }
    __syncthreads();
  }
  float mu = s1[0] * (1.f / 96.f);
  float var = s2[0] * (1.f / 96.f) - mu * mu;
  float rs = rsqrtf(var + 1e-5f);
  if (c < 96) xw[(size_t)t * 96 + c] = (u16t)f2bf((v - mu) * rs * lw[c] + lb[c]);
}

// ---------- kernel 2a: qkv weights -> bf16 (both heads) ----------
__global__ __launch_bounds__(256)
void k_qprep(const float* __restrict__ w0, const float* __restrict__ w1,
             u16t* __restrict__ wq) {
  int e = blockIdx.x * 256 + threadIdx.x;
  if (e >= 2 * 27648) return;
  wq[e] = (u16t)f2bf(e < 27648 ? w0[e] : w1[e - 27648]);
}

// ---------- kernel 2b: qkv GEMM via MFMA (M=50176 tokens, N=288 co, K=96) ----------
// 4 waves/block; wave: 16 tokens x 288 co (18 frags), bf16 out.
__global__ __launch_bounds__(256)
void k_qkv_mfma(const u16t* __restrict__ xw, const u16t* __restrict__ wq,
                const float* __restrict__ bias, u16t* __restrict__ qbuf) {
  int tid = threadIdx.x;
  int lane = tid & 63, wv = tid >> 6;
  int c = lane & 15, lg = lane >> 4;
  int t = blockIdx.x * 64 + wv * 16 + c;
  const u16t* bp = xw + (size_t)t * 96 + lg * 8;
  short8 bv[3];
  #pragma unroll
  for (int kc = 0; kc < 3; ++kc)
    bv[kc] = *reinterpret_cast<const short8*>(bp + kc * 32);
  f32x4 acc[18];
  #pragma unroll
  for (int f = 0; f < 18; ++f) acc[f] = (f32x4){0.f, 0.f, 0.f, 0.f};
  #pragma unroll
  for (int kc = 0; kc < 3; ++kc) {
    #pragma unroll
    for (int f = 0; f < 18; ++f) {
      short8 av = *reinterpret_cast<const short8*>(
          wq + (size_t)(f * 16 + c) * 96 + kc * 32 + lg * 8);
      acc[f] = __builtin_amdgcn_mfma_f32_16x16x32_bf16(av, bv[kc], acc[f], 0, 0, 0);
    }
  }
  u16t* op = qbuf + (size_t)t * 288;
  #pragma unroll
  for (int f = 0; f < 18; ++f) {
    int co = f * 16 + lg * 4;
    float4 bb = *reinterpret_cast<const float4*>(bias + co);
    uint2 st = make_uint2(pack2(acc[f][0] + bb.x, acc[f][1] + bb.y),
                          pack2(acc[f][2] + bb.z, acc[f][3] + bb.w));
    *reinterpret_cast<uint2*>(op + co) = st;
  }
}

// ---------- kernel 3: MFMA window attention (bf16 qkv in, bf16 out) ----------
template<int H, int DH>
__global__ __launch_bounds__(256)
void k_attn_mfma(const u16t* __restrict__ qkvb, const float* __restrict__ rpb,
                 u16t* __restrict__ aot) {
  constexpr float SCALE = (DH == 32) ? 0.17677669529663689f : 0.25f;
  constexpr int NT = DH / 16;  // output dh-tiles
  __shared__ __align__(16) u16t Ks[400 * 32];    // [tok][32] XOR-swizzled chunks
  __shared__ __align__(16) u16t VTs[32 * 408];   // [dh][tok], stride 408
  __shared__ float rpbs[2535];
  __shared__ int Ts[400];
  __shared__ int RGs[400];

  int blk = blockIdx.x;
  int win = blk / H, head = blk % H;
  int wrem = win & 63;
  int hwin = wrem >> 3, wwin = wrem & 7;
  int tid = threadIdx.x;
  int lane = tid & 63, wv = tid >> 6;
  int c = lane & 15, lg = lane >> 4;
  size_t wbase = (size_t)win * NTOK * 288;
  int hoff = (DH == 32) ? head * 32 : 96 + head * 16;   // column base in aot

  {  // zero Ks, VTs (pads must be 0)
    uint4 z = make_uint4(0u, 0u, 0u, 0u);
    uint4* k4 = (uint4*)Ks;
    for (int i = tid; i < 1600; i += 256) k4[i] = z;
    uint4* v4 = (uint4*)VTs;
    for (int i = tid; i < 1632; i += 256) v4[i] = z;
  }
  __syncthreads();
  for (int u = tid; u < NTOK * DH; u += 256) {
    int j = u / DH, d = u % DH;
    u16t kv = qkvb[wbase + (size_t)j * 288 + 96 + head * DH + d];
    u16t vv = qkvb[wbase + (size_t)j * 288 + 192 + head * DH + d];
    int schunk = (d >> 3) ^ (j & 3);
    Ks[j * 32 + schunk * 8 + (d & 7)] = kv;
    VTs[d * 408 + j] = vv;
  }
  for (int i = tid; i < 2535; i += 256) rpbs[i] = rpb[i * H + head];
  for (int j = tid; j < 400; j += 256) {
    if (j < NTOK) {
      int ld = j / 49, r = j % 49, lh = r / 7, lw = r % 7;
      Ts[j] = ld * 169 + lh * 13 + lw;
      int hp = hwin * 7 + lh, wp = wwin * 7 + lw;
      int rd = (ld < 4) ? 1 : 2;
      int rh = (hp < 49) ? 0 : ((hp < 53) ? 1 : 2);
      int rw = (wp < 49) ? 0 : ((wp < 53) ? 1 : 2);
      RGs[j] = rd * 9 + rh * 3 + rw;
    } else { Ts[j] = 0; RGs[j] = 255; }
  }
  __syncthreads();

  for (int qt = wv; qt < 25; qt += 4) {
    int qtok = qt * 16 + c;
    int qcl = (qtok < NTOK) ? qtok : NTOK - 1;
    int Tq = Ts[qcl], rgq = RGs[qcl];
    short8 bq;
    {
      const u16t* qp = qkvb + wbase + (size_t)qcl * 288 + head * DH;
      union { u32t u[4]; short8 v; } bu;
      #pragma unroll
      for (int i2 = 0; i2 < 4; ++i2) {
        u16t e0 = (DH == 32 || lg < 2) ? qp[lg * 8 + 2 * i2] : (u16t)0;
        u16t e1 = (DH == 32 || lg < 2) ? qp[lg * 8 + 2 * i2 + 1] : (u16t)0;
        bu.u[i2] = (u32t)e0 | ((u32t)e1 << 16);
      }
      bq = bu.v;
    }
    f32x4 p[26];
    p[25] = (f32x4){0.f, 0.f, 0.f, 0.f};
    float lmax = -1e30f;
    #pragma unroll
    for (int t = 0; t < 25; ++t) {
      short8 av = *reinterpret_cast<const short8*>(
          &Ks[(16 * t + c) * 32 + ((lg ^ (c & 3)) * 8)]);
      f32x4 acc = (f32x4){0.f, 0.f, 0.f, 0.f};
      acc = __builtin_amdgcn_mfma_f32_16x16x32_bf16(av, bq, acc, 0, 0, 0);
      #pragma unroll
      for (int j = 0; j < 4; ++j) {
        int k = 16 * t + lg * 4 + j;
        float sv = acc[j] * SCALE + rpbs[Tq - Ts[k] + 1267]
                 + ((RGs[k] != rgq) ? -100.f : 0.f);
        if (k >= NTOK) sv = -1e30f;
        p[t][j] = sv;
        lmax = fmaxf(lmax, sv);
      }
    }
    lmax = fmaxf(lmax, __shfl_xor(lmax, 16));
    lmax = fmaxf(lmax, __shfl_xor(lmax, 32));
    float lsum = 0.f;
    #pragma unroll
    for (int t = 0; t < 25; ++t) {
      #pragma unroll
      for (int j = 0; j < 4; ++j) {
        float e = __expf(p[t][j] - lmax);
        p[t][j] = e;
        lsum += e;
      }
    }
    lsum += __shfl_xor(lsum, 16);
    lsum += __shfl_xor(lsum, 32);
    float inv = 1.f / lsum;
    f32x4 oacc[NT];
    #pragma unroll
    for (int ot = 0; ot < NT; ++ot) oacc[ot] = (f32x4){0.f, 0.f, 0.f, 0.f};
    int srcl = ((lane >> 4) & 1) * 32 + c;
    #pragma unroll
    for (int s = 0; s < 13; ++s) {
      u32t pk0x = pack2(p[2 * s][0], p[2 * s][1]);
      u32t pk0y = pack2(p[2 * s][2], p[2 * s][3]);
      u32t pk1x = pack2(p[2 * s + 1][0], p[2 * s + 1][1]);
      u32t pk1y = pack2(p[2 * s + 1][2], p[2 * s + 1][3]);
      u32t ax = (u32t)__shfl((int)pk0x, srcl),      ay = (u32t)__shfl((int)pk0y, srcl);
      u32t bx = (u32t)__shfl((int)pk0x, srcl + 16), by = (u32t)__shfl((int)pk0y, srcl + 16);
      u32t cx = (u32t)__shfl((int)pk1x, srcl),      cy = (u32t)__shfl((int)pk1y, srcl);
      u32t dx = (u32t)__shfl((int)pk1x, srcl + 16), dy = (u32t)__shfl((int)pk1y, srcl + 16);
      bool hi = (lane & 32) != 0;
      union { u32t u[4]; short8 v; } au;
      au.u[0] = hi ? cx : ax; au.u[1] = hi ? cy : ay;
      au.u[2] = hi ? dx : bx; au.u[3] = hi ? dy : by;
      #pragma unroll
      for (int ot = 0; ot < NT; ++ot) {
        short8 bv = *reinterpret_cast<const short8*>(
            &VTs[(ot * 16 + c) * 408 + 32 * s + lg * 8]);
        oacc[ot] = __builtin_amdgcn_mfma_f32_16x16x32_bf16(au.v, bv, oacc[ot], 0, 0, 0);
      }
    }
    float invj[4];
    #pragma unroll
    for (int j = 0; j < 4; ++j) invj[j] = __shfl(inv, lg * 4 + j);
    #pragma unroll
    for (int j = 0; j < 4; ++j) {
      int q = qt * 16 + lg * 4 + j;
      if (q < NTOK) {
        #pragma unroll
        for (int ot = 0; ot < NT; ++ot)
          aot[(size_t)(win * NTOK + q) * 192 + hoff + ot * 16 + c] =
              (u16t)f2bf(oacc[ot][j] * invj[j]);
      }
    }
  }
}

// ---------- kernel 4a: combined proj weights (alpha folded), bf16 ----------
__global__ __launch_bounds__(256)
void k_pprep(const float* __restrict__ pw0, const float* __restrict__ pb0,
             const float* __restrict__ pw1, const float* __restrict__ pb1,
             const float* __restrict__ alpha,
             u16t* __restrict__ wp, float* __restrict__ bp) {
  int e = blockIdx.x * 256 + threadIdx.x;
  if (e >= WPROJ_N) return;
  float al0 = alpha[0], al1 = alpha[1];
  float m = fmaxf(al0, al1);
  float e0 = expf(al0 - m), e1 = expf(al1 - m);
  float aw0 = e0 / (e0 + e1), aw1 = e1 / (e0 + e1);
  int co = e / 192, k = e % 192;
  float v = (k < 96) ? aw0 * pw0[co * 96 + k] : aw1 * pw1[co * 96 + k - 96];
  wp[e] = (u16t)f2bf(v);
  if (e < 96) bp[e] = aw0 * pb0[e] + aw1 * pb1[e];
}

// ---------- kernel 4b: proj via MFMA + window reverse + unshift + residual ----------
__global__ __launch_bounds__(64)
void k_proj_mfma(const u16t* __restrict__ aot, const u16t* __restrict__ wp,
                 const float* __restrict__ bp, const float* __restrict__ x,
                 float* __restrict__ x1) {
  int lane = threadIdx.x;
  int c = lane & 15, lg = lane >> 4;
  int t = blockIdx.x * 16 + c;
  int win = t / NTOK, n = t % NTOK;
  int b = win >> 6, wrem = win & 63;
  int hwin = wrem >> 3, wwin = wrem & 7;
  int ld = n / 49, r = n % 49, lh = r / 7, lw = r % 7;
  int d = (ld + 4) & 7;
  int h = (hwin * 7 + lh + 3) % 56;
  int w = (wwin * 7 + lw + 3) % 56;
  size_t base = (size_t)b * 96 * SPAT + d * 3136 + h * 56 + w;

  const u16t* ap = aot + (size_t)t * 192 + lg * 8;
  f32x4 acc[6];
  #pragma unroll
  for (int f = 0; f < 6; ++f) acc[f] = (f32x4){0.f, 0.f, 0.f, 0.f};
  #pragma unroll
  for (int kc = 0; kc < 6; ++kc) {
    short8 bv = *reinterpret_cast<const short8*>(ap + kc * 32);
    #pragma unroll
    for (int f = 0; f < 6; ++f) {
      short8 av = *reinterpret_cast<const short8*>(wp + (f * 16 + c) * 192 + kc * 32 + lg * 8);
      acc[f] = __builtin_amdgcn_mfma_f32_16x16x32_bf16(av, bv, acc[f], 0, 0, 0);
    }
  }
  #pragma unroll
  for (int f = 0; f < 6; ++f) {
    #pragma unroll
    for (int j = 0; j < 4; ++j) {
      int co = f * 16 + lg * 4 + j;
      size_t idx = base + (size_t)co * SPAT;
      x1[idx] = x[idx] + acc[f][j] + bp[co];
    }
  }
}

// ---------- kernel 5a: zero xpad ----------
__global__ __launch_bounds__(256)
void k_zero(uint4* __restrict__ p, int n) {
  int i = blockIdx.x * 256 + threadIdx.x;
  if (i < n) p[i] = make_uint4(0u, 0u, 0u, 0u);
}

// ---------- kernel 5b: combined FFN weights (softmax-alpha folded), bf16 ----------
__global__ __launch_bounds__(256)
void k_wprep(const float* __restrict__ c3w, const float* __restrict__ c3b,
             const float* __restrict__ c1w, const float* __restrict__ c1b,
             const float* __restrict__ dww, const float* __restrict__ dwb,
             const float* __restrict__ alpha,
             u16t* __restrict__ wcomb, float* __restrict__ bcomb) {
  int e = blockIdx.x * 256 + threadIdx.x;
  if (e >= WCOMB_N) return;
  float a0 = alpha[0], a1 = alpha[1], a2 = alpha[2], a3 = alpha[3];
  float mx = fmaxf(fmaxf(a0, a1), fmaxf(a2, a3));
  float e0 = expf(a0 - mx), e1 = expf(a1 - mx), e2 = expf(a2 - mx), e3 = expf(a3 - mx);
  float inv = 1.f / (e0 + e1 + e2 + e3);
  float f0 = e0 * inv, f1 = e1 * inv, f2 = e2 * inv, f3 = e3 * inv;
  int ko = e / 9216, rm = e % 9216, co = rm / 96, ci = rm % 96;
  float v = f0 * c3w[(co * 96 + ci) * 27 + ko];
  if (ko == 13) v += f1 * c1w[co * 96 + ci];
  if (ci == co) v += f2 * dww[co * 27 + ko];
  if (ko == 13 && ci == co) v += f3;
  wcomb[e] = (u16t)f2bf(v);
  if (e < 96) bcomb[e] = f0 * c3b[e] + f1 * c1b[e] + f2 * dwb[e];
}

// ---------- kernel 5c: LN2 -> padded bf16 tensor ----------
__global__ __launch_bounds__(256)
void k_ln2pad(const float* __restrict__ x1, const float* __restrict__ lw,
              const float* __restrict__ lb, u16t* __restrict__ xpad) {
  int p = blockIdx.x * 256 + threadIdx.x;       // 0..50175
  int b = p / SPAT, s = p % SPAT;
  int d = s / 3136, r = s % 3136, h = r / 56, w = r % 56;
  const float* xp = x1 + (size_t)b * 96 * SPAT + s;
  float sum = 0.f, sq = 0.f;
  #pragma unroll 8
  for (int c = 0; c < 96; ++c) {
    float v = xp[(size_t)c * SPAT];
    sum += v; sq += v * v;
  }
  float mu = sum * (1.f / 96.f);
  float var = sq * (1.f / 96.f) - mu * mu;
  float rs = rsqrtf(var + 1e-5f);
  u16t* op = xpad + (size_t)b * 96 * PSPAT + (d + 1) * PHW + (h + 1) * PW + (w + 1);
  #pragma unroll 8
  for (int c = 0; c < 96; ++c) {
    float v = xp[(size_t)c * SPAT];
    op[(size_t)c * PSPAT] = (u16t)f2bf((v - mu) * rs * lw[c] + lb[c]);
  }
}

// ---------- kernel 6: FFN implicit GEMM via MFMA ----------
// 784 blocks (XCD-swizzled) x 128 thr (2 waves). Wave: 32 spatial x 96 co.
// wcomb ko-slice double-buffered in LDS (padded rows 104).
__global__ __launch_bounds__(128)
void k_ffn_mfma(const u16t* __restrict__ xpad, const u16t* __restrict__ wcomb,
                const float* __restrict__ bcomb, float* __restrict__ out) {
  __shared__ __align__(16) u16t wls[2][96 * 104];
  int tid = threadIdx.x;
  int lane = tid & 63, wv = tid >> 6;
  int c = lane & 15, kg = lane >> 4;
  int bid = blockIdx.x;
  int swz = (bid & 7) * 98 + (bid >> 3);   // bijective: 784 = 8*98
  int pbase[2], obase[2];
  #pragma unroll
  for (int nt = 0; nt < 2; ++nt) {
    int m = swz * 64 + wv * 32 + nt * 16 + c;
    int b = m / SPAT, r = m % SPAT;
    int d = r / 3136, r2 = r % 3136, h = r2 / 56, w = r2 % 56;
    pbase[nt] = b * (96 * PSPAT) + d * PHW + h * PW + w + kg * 8 * PSPAT;
    obase[nt] = b * (96 * SPAT) + r;
  }
  f32x4 acc[2][6];
  #pragma unroll
  for (int nt = 0; nt < 2; ++nt)
    #pragma unroll
    for (int f = 0; f < 6; ++f) acc[nt][f] = (f32x4){0.f, 0.f, 0.f, 0.f};

  // stage ko=0
  {
    const uint4* src = (const uint4*)(wcomb);
    for (int e = tid; e < 1152; e += 128) {
      uint4 v = src[e];
      int co = (e * 8) / 96, ci = (e * 8) % 96;
      *reinterpret_cast<uint4*>(&wls[0][co * 104 + ci]) = v;
    }
  }
  __syncthreads();
  int buf = 0;
  for (int ko = 0; ko < 27; ++ko) {
    int kd = ko / 9, kh = (ko / 3) % 3, kw = ko % 3;
    if (ko + 1 < 27) {
      const uint4* src = (const uint4*)(wcomb + (ko + 1) * 9216);
      for (int e = tid; e < 1152; e += 128) {
        uint4 v = src[e];
        int co = (e * 8) / 96, ci = (e * 8) % 96;
        *reinterpret_cast<uint4*>(&wls[buf ^ 1][co * 104 + ci]) = v;
      }
    }
    #pragma unroll
    for (int cc = 0; cc < 3; ++cc) {
      short8 bv[2];
      #pragma unroll
      for (int nt = 0; nt < 2; ++nt) {
        const u16t* bp = xpad + pbase[nt] + kd * PHW + kh * PW + kw + cc * 32 * PSPAT;
        u32t uu[8];
        #pragma unroll
        for (int i = 0; i < 8; ++i) uu[i] = bp[i * PSPAT];
        union { u32t u[4]; short8 v; } bu;
        #pragma unroll
        for (int j = 0; j < 4; ++j) bu.u[j] = uu[2 * j] | (uu[2 * j + 1] << 16);
        bv[nt] = bu.v;
      }
      #pragma unroll
      for (int f = 0; f < 6; ++f) {
        short8 av = *reinterpret_cast<const short8*>(
            &wls[buf][(f * 16 + c) * 104 + cc * 32 + kg * 8]);
        acc[0][f] = __builtin_amdgcn_mfma_f32_16x16x32_bf16(av, bv[0], acc[0][f], 0, 0, 0);
        acc[1][f] = __builtin_amdgcn_mfma_f32_16x16x32_bf16(av, bv[1], acc[1][f], 0, 0, 0);
      }
    }
    __syncthreads();
    buf ^= 1;
  }
  #pragma unroll
  for (int nt = 0; nt < 2; ++nt)
    #pragma unroll
    for (int f = 0; f < 6; ++f)
      #pragma unroll
      for (int j = 0; j < 4; ++j) {
        int co = f * 16 + kg * 4 + j;
        float* o = out + obase[nt] + co * SPAT;
        *o = *o + acc[nt][f][j] + bcomb[co];
      }
}

extern "C" void kernel_launch(void* const* d_in, const int* in_sizes, int n_in,
                              void* d_out, int out_size, void* d_ws, size_t ws_size,
                              hipStream_t stream) {
  (void)in_sizes; (void)n_in; (void)out_size; (void)ws_size;
  const float* x      = (const float*)d_in[0];
  const float* ln1w   = (const float*)d_in[1];
  const float* ln1b   = (const float*)d_in[2];
  const float* ln2w   = (const float*)d_in[3];
  const float* ln2b   = (const float*)d_in[4];
  const float* qkvw0  = (const float*)d_in[5];
  const float* qkvb0  = (const float*)d_in[6];
  const float* projw0 = (const float*)d_in[7];
  const float* projb0 = (const float*)d_in[8];
  const float* rpb0   = (const float*)d_in[9];
  const float* qkvw1  = (const float*)d_in[10];
  const float* qkvb1  = (const float*)d_in[11];
  const float* projw1 = (const float*)d_in[12];
  const float* projb1 = (const float*)d_in[13];
  const float* rpb1   = (const float*)d_in[14];
  const float* aattn  = (const float*)d_in[15];
  const float* c3w    = (const float*)d_in[16];
  const float* c3b    = (const float*)d_in[17];
  const float* c1w    = (const float*)d_in[18];
  const float* c1b    = (const float*)d_in[19];
  const float* dww    = (const float*)d_in[20];
  const float* dwb    = (const float*)d_in[21];
  const float* affn   = (const float*)d_in[22];

  // workspace (u16 units): [xw | aot | qbuf | wq]; qbuf region reused for xpad etc.
  u16t* u    = (u16t*)d_ws;
  u16t* xw   = u;                                  // 50176*96
  u16t* aot  = xw + (size_t)NTOKTOT * 96;          // 50176*192
  u16t* qbuf = aot + (size_t)NTOKTOT * 192;        // 50176*288
  u16t* wq   = qbuf + (size_t)NTOKTOT * 288;       // 2*27648
  u16t* xpad  = qbuf;                              // reuse (dead after attn)
  u16t* wcomb = xpad + XPAD_U16;
  float* bcomb = (float*)(wcomb + WCOMB_N);
  u16t* wproj = (u16t*)(bcomb + 96);
  float* bproj = (float*)(wproj + WPROJ_N);
  float* x1  = (float*)d_out;

  k_ln1_win<<<NWIN * NTOK, 128, 0, stream>>>(x, ln1w, ln1b, xw);
  k_qprep<<<216, 256, 0, stream>>>(qkvw0, qkvw1, wq);
  k_qkv_mfma<<<784, 256, 0, stream>>>(xw, wq, qkvb0, qbuf);
  k_attn_mfma<3, 32><<<NWIN * 3, 256, 0, stream>>>(qbuf, rpb0, aot);
  k_qkv_mfma<<<784, 256, 0, stream>>>(xw, wq + 27648, qkvb1, qbuf);
  k_attn_mfma<6, 16><<<NWIN * 6, 256, 0, stream>>>(qbuf, rpb1, aot);
  // qbuf dead: build xpad / combined weights in its place
  k_zero<<<(XPAD_U16 / 8 + 255) / 256, 256, 0, stream>>>((uint4*)xpad, XPAD_U16 / 8);
  k_wprep<<<(WCOMB_N + 255) / 256, 256, 0, stream>>>(c3w, c3b, c1w, c1b, dww, dwb,
                                                     affn, wcomb, bcomb);
  k_pprep<<<(WPROJ_N + 255) / 256, 256, 0, stream>>>(projw0, projb0, projw1, projb1,
                                                     aattn, wproj, bproj);
  k_proj_mfma<<<3136, 64, 0, stream>>>(aot, wproj, bproj, x, x1);
  k_ln2pad<<<196, 256, 0, stream>>>(x1, ln2w, ln2b, xpad);
  k_ffn_mfma<<<784, 128, 0, stream>>>(xpad, wcomb, bcomb, (float*)d_out);
}

// Round 6
// 503.237 us; speedup vs baseline: 14.2229x; 1.0476x over previous
//
#include <hip/hip_runtime.h>

#define NWIN 128       // B * nW windows
#define NTOK 392       // tokens per window (8*7*7)
#define SPAT 25088     // D*H*W
#define NELEM 4816896  // 2*96*25088

typedef unsigned short u16t;
typedef unsigned int u32t;
typedef __attribute__((ext_vector_type(8))) short short8;
typedef __attribute__((ext_vector_type(4))) float f32x4;

// xpad geometry: [b][ci][10][58][58] bf16, zero border
#define PW 58
#define PHW 3364      // 58*58
#define PSPAT 33640   // 10*58*58
#define XPAD_U16 6458880   // 2*96*33640
#define WCOMB_N 248832     // 27*96*96
#define WPROJ_N 18432      // 96*192
#define NTOKTOT 50176      // NWIN*NTOK

// ---------- helpers ----------
__device__ __forceinline__ unsigned int f2bf(float f) {
  unsigned int u = __float_as_uint(f);
  return (u + 0x7fffu + ((u >> 16) & 1u)) >> 16;   // RNE to bf16
}
__device__ __forceinline__ unsigned int pack2(float a, float b) {
  return f2bf(a) | (f2bf(b) << 16);
}
__device__ __forceinline__ float bflo(unsigned int u) { return __uint_as_float(u << 16); }
__device__ __forceinline__ float bfhi(unsigned int u) { return __uint_as_float(u & 0xffff0000u); }

// ---------- kernel 1: LN1 over C + roll(-4,-3,-3) + window partition (bf16 out) ----------
__global__ __launch_bounds__(128)
void k_ln1_win(const float* __restrict__ x, const float* __restrict__ lw,
               const float* __restrict__ lb, u16t* __restrict__ xw) {
  __shared__ float s1[128], s2[128];
  int t = blockIdx.x;                 // destination token
  int win = t / NTOK, n = t % NTOK;
  int b = win >> 6, wrem = win & 63;
  int hwin = wrem >> 3, wwin = wrem & 7;
  int ld = n / 49, r = n % 49, lh = r / 7, lw2 = r % 7;
  int d = (ld + 4) & 7;                       // shifted -> source coords
  int h = (hwin * 7 + lh + 3) % 56;
  int w = (wwin * 7 + lw2 + 3) % 56;
  size_t base = (size_t)b * 96 * SPAT + d * 3136 + h * 56 + w;
  int c = threadIdx.x;
  float v = (c < 96) ? x[base + (size_t)c * SPAT] : 0.f;
  s1[c] = v; s2[c] = v * v;
  __syncthreads();
  #pragma unroll
  for (int st = 64; st > 0; st >>= 1) {
    if (c < st) { s1[c] += s1[c + st]; s2[c] += s2[c + st]; }
    __syncthreads();
  }
  float mu = s1[0] * (1.f / 96.f);
  float var = s2[0] * (1.f / 96.f) - mu * mu;
  float rs = rsqrtf(var + 1e-5f);
  if (c < 96) xw[(size_t)t * 96 + c] = (u16t)f2bf((v - mu) * rs * lw[c] + lb[c]);
}

// ---------- kernel 2a: qkv weights -> bf16 (both heads) ----------
__global__ __launch_bounds__(256)
void k_qprep(const float* __restrict__ w0, const float* __restrict__ w1,
             u16t* __restrict__ wq) {
  int e = blockIdx.x * 256 + threadIdx.x;
  if (e >= 2 * 27648) return;
  wq[e] = (u16t)f2bf(e < 27648 ? w0[e] : w1[e - 27648]);
}

// ---------- kernel 2b: qkv GEMM via MFMA (M=50176 tokens, N=288 co, K=96) ----------
__global__ __launch_bounds__(256)
void k_qkv_mfma(const u16t* __restrict__ xw, const u16t* __restrict__ wq,
                const float* __restrict__ bias, u16t* __restrict__ qbuf) {
  int tid = threadIdx.x;
  int lane = tid & 63, wv = tid >> 6;
  int c = lane & 15, lg = lane >> 4;
  int t = blockIdx.x * 64 + wv * 16 + c;
  const u16t* bp = xw + (size_t)t * 96 + lg * 8;
  short8 bv[3];
  #pragma unroll
  for (int kc = 0; kc < 3; ++kc)
    bv[kc] = *reinterpret_cast<const short8*>(bp + kc * 32);
  f32x4 acc[18];
  #pragma unroll
  for (int f = 0; f < 18; ++f) acc[f] = (f32x4){0.f, 0.f, 0.f, 0.f};
  #pragma unroll
  for (int kc = 0; kc < 3; ++kc) {
    #pragma unroll
    for (int f = 0; f < 18; ++f) {
      short8 av = *reinterpret_cast<const short8*>(
          wq + (size_t)(f * 16 + c) * 96 + kc * 32 + lg * 8);
      acc[f] = __builtin_amdgcn_mfma_f32_16x16x32_bf16(av, bv[kc], acc[f], 0, 0, 0);
    }
  }
  u16t* op = qbuf + (size_t)t * 288;
  #pragma unroll
  for (int f = 0; f < 18; ++f) {
    int co = f * 16 + lg * 4;
    float4 bb = *reinterpret_cast<const float4*>(bias + co);
    uint2 st = make_uint2(pack2(acc[f][0] + bb.x, acc[f][1] + bb.y),
                          pack2(acc[f][2] + bb.z, acc[f][3] + bb.w));
    *reinterpret_cast<uint2*>(op + co) = st;
  }
}

// ---------- kernel 2c: precompute bias+mask tables, bf16 [H][4][392][400] ----------
template<int H>
__global__ __launch_bounds__(256)
void k_bprep(const float* __restrict__ rpb, u16t* __restrict__ bm) {
  int e = blockIdx.x * 256 + threadIdx.x;
  if (e >= H * 4 * 392 * 400) return;
  int k = e % 400;
  int q = (e / 400) % 392;
  int v = (e / (400 * 392)) % 4;
  int head = e / (400 * 392 * 4);
  if (k >= 392) { bm[e] = 0; return; }
  int ldq = q / 49, rq = q % 49, lhq = rq / 7, lwq = rq % 7;
  int ldk = k / 49, rk = k % 49, lhk = rk / 7, lwk = rk % 7;
  int diff = (ldq - ldk + 7) * 169 + (lhq - lhk + 6) * 13 + (lwq - lwk + 6);
  float bias = rpb[diff * H + head];
  int vh = v >> 1, vw = v & 1;
  int rgq = ((ldq < 4) ? 1 : 2) * 9 + (vh ? ((lhq < 4) ? 1 : 2) : 0) * 3
          + (vw ? ((lwq < 4) ? 1 : 2) : 0);
  int rgk = ((ldk < 4) ? 1 : 2) * 9 + (vh ? ((lhk < 4) ? 1 : 2) : 0) * 3
          + (vw ? ((lwk < 4) ? 1 : 2) : 0);
  bm[e] = (u16t)f2bf(bias + ((rgq != rgk) ? -100.f : 0.f));
}

// ---------- kernel 3: MFMA window attention, online softmax ----------
// Block = (window, head, qpart). Swapped QK^T; defer-rescale online softmax;
// bias+mask from precomputed global table.
template<int H, int DH>
__global__ __launch_bounds__(256, (DH == 16) ? 4 : 3)
void k_attn_mfma(const u16t* __restrict__ qkvb, const u16t* __restrict__ bm,
                 u16t* __restrict__ aot) {
  constexpr float SCALE = (DH == 32) ? 0.17677669529663689f : 0.25f;
  constexpr int NT = DH / 16;          // output dh-tiles
  constexpr int QSPLIT = (DH == 16) ? 4 : 2;
  __shared__ __align__(16) u16t Ks[400 * 32];     // [tok][32] XOR-swizzled chunks
  __shared__ __align__(16) u16t VTs[DH * 416];    // [dh][tok], stride 416

  int blk = blockIdx.x;
  int part = blk % QSPLIT;
  int wh = blk / QSPLIT;
  int win = wh / H, head = wh % H;
  int wrem = win & 63;
  int hwin = wrem >> 3, wwin = wrem & 7;
  int tid = threadIdx.x;
  int lane = tid & 63, wv = tid >> 6;
  int c = lane & 15, lg = lane >> 4;
  size_t wbase = (size_t)win * NTOK * 288;
  int hoff = (DH == 32) ? head * 32 : 96 + head * 16;   // column base in aot
  int variant = ((hwin == 7) ? 2 : 0) | ((wwin == 7) ? 1 : 0);
  const u16t* bmh = bm + ((size_t)(head * 4 + variant) * 392) * 400;

  {  // zero K/V (pads must be 0)
    uint4 z = make_uint4(0u, 0u, 0u, 0u);
    uint4* k4 = (uint4*)Ks;
    for (int i = tid; i < 1600; i += 256) k4[i] = z;
    uint4* v4 = (uint4*)VTs;
    for (int i = tid; i < DH * 52; i += 256) v4[i] = z;
  }
  __syncthreads();
  constexpr int DG = DH / 8;
  for (int u = tid; u < NTOK * DG; u += 256) {
    int j = u / DG, dg = u % DG;
    const u16t* kp = qkvb + wbase + (size_t)j * 288 + 96 + head * DH + dg * 8;
    uint4 kv = *reinterpret_cast<const uint4*>(kp);
    int sch = dg ^ (j & 3);
    *reinterpret_cast<uint4*>(&Ks[j * 32 + sch * 8]) = kv;
    const u16t* vp = qkvb + wbase + (size_t)j * 288 + 192 + head * DH + dg * 8;
    union { uint4 q; u16t s[8]; } vv;
    vv.q = *reinterpret_cast<const uint4*>(vp);
    #pragma unroll
    for (int ee = 0; ee < 8; ++ee) VTs[(dg * 8 + ee) * 416 + j] = vv.s[ee];
  }
  __syncthreads();

  // q-tile range for this part
  constexpr int QBASE = 25 / QSPLIT;
  constexpr int QREM = 25 % QSPLIT;
  int q0 = part * QBASE + ((part < QREM) ? part : QREM);
  int q1 = q0 + QBASE + ((part < QREM) ? 1 : 0);

  for (int qt = q0 + wv; qt < q1; qt += 4) {
    int qtok = qt * 16 + c;
    int qcl = (qtok < NTOK) ? qtok : NTOK - 1;
    short8 bq;
    {
      const u16t* qp = qkvb + wbase + (size_t)qcl * 288 + head * DH;
      union { u32t u[4]; short8 v; } bu;
      #pragma unroll
      for (int i2 = 0; i2 < 4; ++i2) {
        u16t e0 = (DH == 32 || lg < 2) ? qp[lg * 8 + 2 * i2] : (u16t)0;
        u16t e1 = (DH == 32 || lg < 2) ? qp[lg * 8 + 2 * i2 + 1] : (u16t)0;
        bu.u[i2] = (u32t)e0 | ((u32t)e1 << 16);
      }
      bq = bu.v;
    }
    const u16t* brow = bmh + (size_t)qcl * 400;
    float m = -1e30f, lsum = 0.f;
    f32x4 oacc[NT];
    #pragma unroll
    for (int ot = 0; ot < NT; ++ot) oacc[ot] = (f32x4){0.f, 0.f, 0.f, 0.f};
    int srcl = ((lane >> 4) & 1) * 32 + c;
    #pragma unroll
    for (int s = 0; s < 13; ++s) {
      f32x4 p0, p1;
      {
        int t = 2 * s;
        short8 av = *reinterpret_cast<const short8*>(
            &Ks[(16 * t + c) * 32 + ((lg ^ (c & 3)) * 8)]);
        f32x4 a = (f32x4){0.f, 0.f, 0.f, 0.f};
        a = __builtin_amdgcn_mfma_f32_16x16x32_bf16(av, bq, a, 0, 0, 0);
        uint2 bb = *reinterpret_cast<const uint2*>(brow + 16 * t + 4 * lg);
        p0[0] = a[0] * SCALE + bflo(bb.x);
        p0[1] = a[1] * SCALE + bfhi(bb.x);
        p0[2] = a[2] * SCALE + bflo(bb.y);
        p0[3] = a[3] * SCALE + bfhi(bb.y);
      }
      if (s < 12) {
        int t = 2 * s + 1;
        short8 av = *reinterpret_cast<const short8*>(
            &Ks[(16 * t + c) * 32 + ((lg ^ (c & 3)) * 8)]);
        f32x4 a = (f32x4){0.f, 0.f, 0.f, 0.f};
        a = __builtin_amdgcn_mfma_f32_16x16x32_bf16(av, bq, a, 0, 0, 0);
        uint2 bb = *reinterpret_cast<const uint2*>(brow + 16 * t + 4 * lg);
        p1[0] = a[0] * SCALE + bflo(bb.x);
        p1[1] = a[1] * SCALE + bfhi(bb.x);
        p1[2] = a[2] * SCALE + bflo(bb.y);
        p1[3] = a[3] * SCALE + bfhi(bb.y);
      } else {
        p1 = (f32x4){-1e30f, -1e30f, -1e30f, -1e30f};
        if (lg >= 2) { p0[0] = -1e30f; p0[1] = -1e30f; p0[2] = -1e30f; p0[3] = -1e30f; }
      }
      float pm = fmaxf(fmaxf(fmaxf(p0[0], p0[1]), fmaxf(p0[2], p0[3])),
                       fmaxf(fmaxf(p1[0], p1[1]), fmaxf(p1[2], p1[3])));
      pm = fmaxf(pm, __shfl_xor(pm, 16));
      pm = fmaxf(pm, __shfl_xor(pm, 32));
      float mnew = (pm > m + 8.f) ? pm : m;
      float fac = __expf(m - mnew);          // ==1 when m unchanged; ==0 on first chunk
      lsum *= fac;
      #pragma unroll
      for (int ot = 0; ot < NT; ++ot) oacc[ot] *= fac;
      m = mnew;
      #pragma unroll
      for (int j = 0; j < 4; ++j) {
        p0[j] = __expf(p0[j] - m);
        p1[j] = __expf(p1[j] - m);
      }
      lsum += p0[0] + p0[1] + p0[2] + p0[3] + p1[0] + p1[1] + p1[2] + p1[3];
      u32t pk0x = pack2(p0[0], p0[1]);
      u32t pk0y = pack2(p0[2], p0[3]);
      u32t pk1x = pack2(p1[0], p1[1]);
      u32t pk1y = pack2(p1[2], p1[3]);
      u32t ax = (u32t)__shfl((int)pk0x, srcl),      ay = (u32t)__shfl((int)pk0y, srcl);
      u32t bx = (u32t)__shfl((int)pk0x, srcl + 16), by = (u32t)__shfl((int)pk0y, srcl + 16);
      u32t cx = (u32t)__shfl((int)pk1x, srcl),      cy = (u32t)__shfl((int)pk1y, srcl);
      u32t dx = (u32t)__shfl((int)pk1x, srcl + 16), dy = (u32t)__shfl((int)pk1y, srcl + 16);
      bool hi = (lane & 32) != 0;
      union { u32t u[4]; short8 v; } au;
      au.u[0] = hi ? cx : ax; au.u[1] = hi ? cy : ay;
      au.u[2] = hi ? dx : bx; au.u[3] = hi ? dy : by;
      #pragma unroll
      for (int ot = 0; ot < NT; ++ot) {
        short8 bv = *reinterpret_cast<const short8*>(
            &VTs[(ot * 16 + c) * 416 + 32 * s + lg * 8]);
        oacc[ot] = __builtin_amdgcn_mfma_f32_16x16x32_bf16(au.v, bv, oacc[ot], 0, 0, 0);
      }
    }
    lsum += __shfl_xor(lsum, 16);
    lsum += __shfl_xor(lsum, 32);
    float inv = 1.f / lsum;
    float invj[4];
    #pragma unroll
    for (int j = 0; j < 4; ++j) invj[j] = __shfl(inv, lg * 4 + j);
    #pragma unroll
    for (int j = 0; j < 4; ++j) {
      int q = qt * 16 + lg * 4 + j;
      if (q < NTOK) {
        #pragma unroll
        for (int ot = 0; ot < NT; ++ot)
          aot[(size_t)(win * NTOK + q) * 192 + hoff + ot * 16 + c] =
              (u16t)f2bf(oacc[ot][j] * invj[j]);
      }
    }
  }
}

// ---------- kernel 4a: combined proj weights (alpha folded), bf16 ----------
__global__ __launch_bounds__(256)
void k_pprep(const float* __restrict__ pw0, const float* __restrict__ pb0,
             const float* __restrict__ pw1, const float* __restrict__ pb1,
             const float* __restrict__ alpha,
             u16t* __restrict__ wp, float* __restrict__ bp) {
  int e = blockIdx.x * 256 + threadIdx.x;
  if (e >= WPROJ_N) return;
  float al0 = alpha[0], al1 = alpha[1];
  float m = fmaxf(al0, al1);
  float e0 = expf(al0 - m), e1 = expf(al1 - m);
  float aw0 = e0 / (e0 + e1), aw1 = e1 / (e0 + e1);
  int co = e / 192, k = e % 192;
  float v = (k < 96) ? aw0 * pw0[co * 96 + k] : aw1 * pw1[co * 96 + k - 96];
  wp[e] = (u16t)f2bf(v);
  if (e < 96) bp[e] = aw0 * pb0[e] + aw1 * pb1[e];
}

// ---------- kernel 4b: proj via MFMA + window reverse + unshift + residual ----------
__global__ __launch_bounds__(64)
void k_proj_mfma(const u16t* __restrict__ aot, const u16t* __restrict__ wp,
                 const float* __restrict__ bp, const float* __restrict__ x,
                 float* __restrict__ x1) {
  int lane = threadIdx.x;
  int c = lane & 15, lg = lane >> 4;
  int t = blockIdx.x * 16 + c;
  int win = t / NTOK, n = t % NTOK;
  int b = win >> 6, wrem = win & 63;
  int hwin = wrem >> 3, wwin = wrem & 7;
  int ld = n / 49, r = n % 49, lh = r / 7, lw = r % 7;
  int d = (ld + 4) & 7;
  int h = (hwin * 7 + lh + 3) % 56;
  int w = (wwin * 7 + lw + 3) % 56;
  size_t base = (size_t)b * 96 * SPAT + d * 3136 + h * 56 + w;

  const u16t* ap = aot + (size_t)t * 192 + lg * 8;
  f32x4 acc[6];
  #pragma unroll
  for (int f = 0; f < 6; ++f) acc[f] = (f32x4){0.f, 0.f, 0.f, 0.f};
  #pragma unroll
  for (int kc = 0; kc < 6; ++kc) {
    short8 bv = *reinterpret_cast<const short8*>(ap + kc * 32);
    #pragma unroll
    for (int f = 0; f < 6; ++f) {
      short8 av = *reinterpret_cast<const short8*>(wp + (f * 16 + c) * 192 + kc * 32 + lg * 8);
      acc[f] = __builtin_amdgcn_mfma_f32_16x16x32_bf16(av, bv, acc[f], 0, 0, 0);
    }
  }
  #pragma unroll
  for (int f = 0; f < 6; ++f) {
    #pragma unroll
    for (int j = 0; j < 4; ++j) {
      int co = f * 16 + lg * 4 + j;
      size_t idx = base + (size_t)co * SPAT;
      x1[idx] = x[idx] + acc[f][j] + bp[co];
    }
  }
}

// ---------- kernel 5a: zero xpad ----------
__global__ __launch_bounds__(256)
void k_zero(uint4* __restrict__ p, int n) {
  int i = blockIdx.x * 256 + threadIdx.x;
  if (i < n) p[i] = make_uint4(0u, 0u, 0u, 0u);
}

// ---------- kernel 5b: combined FFN weights (softmax-alpha folded), bf16 ----------
__global__ __launch_bounds__(256)
void k_wprep(const float* __restrict__ c3w, const float* __restrict__ c3b,
             const float* __restrict__ c1w, const float* __restrict__ c1b,
             const float* __restrict__ dww, const float* __restrict__ dwb,
             const float* __restrict__ alpha,
             u16t* __restrict__ wcomb, float* __restrict__ bcomb) {
  int e = blockIdx.x * 256 + threadIdx.x;
  if (e >= WCOMB_N) return;
  float a0 = alpha[0], a1 = alpha[1], a2 = alpha[2], a3 = alpha[3];
  float mx = fmaxf(fmaxf(a0, a1), fmaxf(a2, a3));
  float e0 = expf(a0 - mx), e1 = expf(a1 - mx), e2 = expf(a2 - mx), e3 = expf(a3 - mx);
  float inv = 1.f / (e0 + e1 + e2 + e3);
  float f0 = e0 * inv, f1 = e1 * inv, f2 = e2 * inv, f3 = e3 * inv;
  int ko = e / 9216, rm = e % 9216, co = rm / 96, ci = rm % 96;
  float v = f0 * c3w[(co * 96 + ci) * 27 + ko];
  if (ko == 13) v += f1 * c1w[co * 96 + ci];
  if (ci == co) v += f2 * dww[co * 27 + ko];
  if (ko == 13 && ci == co) v += f3;
  wcomb[e] = (u16t)f2bf(v);
  if (e < 96) bcomb[e] = f0 * c3b[e] + f1 * c1b[e] + f2 * dwb[e];
}

// ---------- kernel 5c: LN2 -> padded bf16 tensor ----------
__global__ __launch_bounds__(256)
void k_ln2pad(const float* __restrict__ x1, const float* __restrict__ lw,
              const float* __restrict__ lb, u16t* __restrict__ xpad) {
  int p = blockIdx.x * 256 + threadIdx.x;       // 0..50175
  int b = p / SPAT, s = p % SPAT;
  int d = s / 3136, r = s % 3136, h = r / 56, w = r % 56;
  const float* xp = x1 + (size_t)b * 96 * SPAT + s;
  float sum = 0.f, sq = 0.f;
  #pragma unroll 8
  for (int c = 0; c < 96; ++c) {
    float v = xp[(size_t)c * SPAT];
    sum += v; sq += v * v;
  }
  float mu = sum * (1.f / 96.f);
  float var = sq * (1.f / 96.f) - mu * mu;
  float rs = rsqrtf(var + 1e-5f);
  u16t* op = xpad + (size_t)b * 96 * PSPAT + (d + 1) * PHW + (h + 1) * PW + (w + 1);
  #pragma unroll 8
  for (int c = 0; c < 96; ++c) {
    float v = xp[(size_t)c * SPAT];
    op[(size_t)c * PSPAT] = (u16t)f2bf((v - mu) * rs * lw[c] + lb[c]);
  }
}

// ---------- kernel 6: FFN implicit GEMM via MFMA ----------
__global__ __launch_bounds__(128)
void k_ffn_mfma(const u16t* __restrict__ xpad, const u16t* __restrict__ wcomb,
                const float* __restrict__ bcomb, float* __restrict__ out) {
  __shared__ __align__(16) u16t wls[2][96 * 104];
  int tid = threadIdx.x;
  int lane = tid & 63, wv = tid >> 6;
  int c = lane & 15, kg = lane >> 4;
  int bid = blockIdx.x;
  int swz = (bid & 7) * 98 + (bid >> 3);   // bijective: 784 = 8*98
  int pbase[2], obase[2];
  #pragma unroll
  for (int nt = 0; nt < 2; ++nt) {
    int m = swz * 64 + wv * 32 + nt * 16 + c;
    int b = m / SPAT, r = m % SPAT;
    int d = r / 3136, r2 = r % 3136, h = r2 / 56, w = r2 % 56;
    pbase[nt] = b * (96 * PSPAT) + d * PHW + h * PW + w + kg * 8 * PSPAT;
    obase[nt] = b * (96 * SPAT) + r;
  }
  f32x4 acc[2][6];
  #pragma unroll
  for (int nt = 0; nt < 2; ++nt)
    #pragma unroll
    for (int f = 0; f < 6; ++f) acc[nt][f] = (f32x4){0.f, 0.f, 0.f, 0.f};

  {
    const uint4* src = (const uint4*)(wcomb);
    for (int e = tid; e < 1152; e += 128) {
      uint4 v = src[e];
      int co = (e * 8) / 96, ci = (e * 8) % 96;
      *reinterpret_cast<uint4*>(&wls[0][co * 104 + ci]) = v;
    }
  }
  __syncthreads();
  int buf = 0;
  for (int ko = 0; ko < 27; ++ko) {
    int kd = ko / 9, kh = (ko / 3) % 3, kw = ko % 3;
    if (ko + 1 < 27) {
      const uint4* src = (const uint4*)(wcomb + (ko + 1) * 9216);
      for (int e = tid; e < 1152; e += 128) {
        uint4 v = src[e];
        int co = (e * 8) / 96, ci = (e * 8) % 96;
        *reinterpret_cast<uint4*>(&wls[buf ^ 1][co * 104 + ci]) = v;
      }
    }
    #pragma unroll
    for (int cc = 0; cc < 3; ++cc) {
      short8 bv[2];
      #pragma unroll
      for (int nt = 0; nt < 2; ++nt) {
        const u16t* bp = xpad + pbase[nt] + kd * PHW + kh * PW + kw + cc * 32 * PSPAT;
        u32t uu[8];
        #pragma unroll
        for (int i = 0; i < 8; ++i) uu[i] = bp[i * PSPAT];
        union { u32t u[4]; short8 v; } bu;
        #pragma unroll
        for (int j = 0; j < 4; ++j) bu.u[j] = uu[2 * j] | (uu[2 * j + 1] << 16);
        bv[nt] = bu.v;
      }
      #pragma unroll
      for (int f = 0; f < 6; ++f) {
        short8 av = *reinterpret_cast<const short8*>(
            &wls[buf][(f * 16 + c) * 104 + cc * 32 + kg * 8]);
        acc[0][f] = __builtin_amdgcn_mfma_f32_16x16x32_bf16(av, bv[0], acc[0][f], 0, 0, 0);
        acc[1][f] = __builtin_amdgcn_mfma_f32_16x16x32_bf16(av, bv[1], acc[1][f], 0, 0, 0);
      }
    }
    __syncthreads();
    buf ^= 1;
  }
  #pragma unroll
  for (int nt = 0; nt < 2; ++nt)
    #pragma unroll
    for (int f = 0; f < 6; ++f)
      #pragma unroll
      for (int j = 0; j < 4; ++j) {
        int co = f * 16 + kg * 4 + j;
        float* o = out + obase[nt] + co * SPAT;
        *o = *o + acc[nt][f][j] + bcomb[co];
      }
}

extern "C" void kernel_launch(void* const* d_in, const int* in_sizes, int n_in,
                              void* d_out, int out_size, void* d_ws, size_t ws_size,
                              hipStream_t stream) {
  (void)in_sizes; (void)n_in; (void)out_size; (void)ws_size;
  const float* x      = (const float*)d_in[0];
  const float* ln1w   = (const float*)d_in[1];
  const float* ln1b   = (const float*)d_in[2];
  const float* ln2w   = (const float*)d_in[3];
  const float* ln2b   = (const float*)d_in[4];
  const float* qkvw0  = (const float*)d_in[5];
  const float* qkvb0  = (const float*)d_in[6];
  const float* projw0 = (const float*)d_in[7];
  const float* projb0 = (const float*)d_in[8];
  const float* rpb0   = (const float*)d_in[9];
  const float* qkvw1  = (const float*)d_in[10];
  const float* qkvb1  = (const float*)d_in[11];
  const float* projw1 = (const float*)d_in[12];
  const float* projb1 = (const float*)d_in[13];
  const float* rpb1   = (const float*)d_in[14];
  const float* aattn  = (const float*)d_in[15];
  const float* c3w    = (const float*)d_in[16];
  const float* c3b    = (const float*)d_in[17];
  const float* c1w    = (const float*)d_in[18];
  const float* c1b    = (const float*)d_in[19];
  const float* dww    = (const float*)d_in[20];
  const float* dwb    = (const float*)d_in[21];
  const float* affn   = (const float*)d_in[22];

  // workspace (u16 units)
  u16t* u    = (u16t*)d_ws;
  u16t* xw   = u;                                  // 50176*96
  u16t* aot  = xw + (size_t)NTOKTOT * 96;          // 50176*192
  u16t* qbuf = aot + (size_t)NTOKTOT * 192;        // 50176*288
  u16t* wq   = qbuf + (size_t)NTOKTOT * 288;       // 2*27648
  u16t* bm0  = wq + 2 * 27648;                     // 3*4*392*400
  u16t* bm1  = bm0 + 3 * 4 * 392 * 400;            // 6*4*392*400
  u16t* xpad  = qbuf;                              // reuse (dead after attn)
  u16t* wcomb = xpad + XPAD_U16;
  float* bcomb = (float*)(wcomb + WCOMB_N);
  u16t* wproj = (u16t*)(bcomb + 96);
  float* bproj = (float*)(wproj + WPROJ_N);
  float* x1  = (float*)d_out;

  k_ln1_win<<<NWIN * NTOK, 128, 0, stream>>>(x, ln1w, ln1b, xw);
  k_qprep<<<216, 256, 0, stream>>>(qkvw0, qkvw1, wq);
  k_bprep<3><<<7350, 256, 0, stream>>>(rpb0, bm0);
  k_bprep<6><<<14700, 256, 0, stream>>>(rpb1, bm1);
  k_qkv_mfma<<<784, 256, 0, stream>>>(xw, wq, qkvb0, qbuf);
  k_attn_mfma<3, 32><<<NWIN * 3 * 2, 256, 0, stream>>>(qbuf, bm0, aot);
  k_qkv_mfma<<<784, 256, 0, stream>>>(xw, wq + 27648, qkvb1, qbuf);
  k_attn_mfma<6, 16><<<NWIN * 6 * 4, 256, 0, stream>>>(qbuf, bm1, aot);
  // qbuf dead: build xpad / combined weights in its place
  k_zero<<<(XPAD_U16 / 8 + 255) / 256, 256, 0, stream>>>((uint4*)xpad, XPAD_U16 / 8);
  k_wprep<<<(WCOMB_N + 255) / 256, 256, 0, stream>>>(c3w, c3b, c1w, c1b, dww, dwb,
                                                     affn, wcomb, bcomb);
  k_pprep<<<(WPROJ_N + 255) / 256, 256, 0, stream>>>(projw0, projb0, projw1, projb1,
                                                     aattn, wproj, bproj);
  k_proj_mfma<<<3136, 64, 0, stream>>>(aot, wproj, bproj, x, x1);
  k_ln2pad<<<196, 256, 0, stream>>>(x1, ln2w, ln2b, xpad);
  k_ffn_mfma<<<784, 128, 0, stream>>>(xpad, wcomb, bcomb, (float*)d_out);
}